// Round 9
// baseline (49.159 us; speedup 1.0000x reference)
//
#include <hip/hip_runtime.h>
#include <math.h>

#define NQ_     14
#define DIM_    16384
#define NB      256
#define NLAYERS 3
#define NPAIR   13
#define NT      1024

// LDS swizzle: XOR bits 1-3 of the float2 index with bits 4-6.
#define SW(k) ((k) ^ ((((k) >> 4) & 7) << 1))

__device__ __forceinline__ float2 cmul(float2 a, float2 b) {
    return make_float2(a.x*b.x - a.y*b.y, a.x*b.y + a.y*b.x);
}

// SU(2) gate: u10 = -conj(u01), u11 = conj(u00) derived via free neg modifiers.
__device__ __forceinline__ void g2s(float2& a0, float2& a1, float2 u00, float2 u01) {
    float2 b0, b1;
    b0.x =  u00.x*a0.x - u00.y*a0.y + u01.x*a1.x - u01.y*a1.y;
    b0.y =  u00.x*a0.y + u00.y*a0.x + u01.x*a1.y + u01.y*a1.x;
    b1.x = -u01.x*a0.x - u01.y*a0.y + u00.x*a1.x + u00.y*a1.y;
    b1.y = -u01.x*a0.y + u01.y*a0.x + u00.x*a1.y - u00.y*a1.x;
    a0 = b0; a1 = b1;
}

#define GATE_BIT(RB, SET, Q) do { \
    float4 uu = s_U4[SET][Q]; \
    float2 u00 = make_float2(uu.x, uu.y), u01 = make_float2(uu.z, uu.w); \
    _Pragma("unroll") \
    for (int j = 0; j < 16; ++j) \
        if (!((j >> (RB)) & 1)) g2s(a[j], a[j | (1 << (RB))], u00, u01); \
} while (0)

// X/Y measurement only (Z handled by the s_GL/s_GH sweep in the final pass).
#define MEASW(RB, WEXPR) do { float xr = 0.f; \
    _Pragma("unroll") for (int j = 0; j < 16; ++j) { \
        if (!((j >> (RB)) & 1)) { \
            int j1 = j | (1 << (RB)); \
            float cr = a[j].x*a[j1].x + a[j].y*a[j1].y; \
            float ci = a[j].x*a[j1].y - a[j].y*a[j1].x; \
            float2 w = (WEXPR); \
            xr += w.x * cr - w.y * ci; \
        } } \
    acc += xr; } while (0)

__global__ __launch_bounds__(NT, 4) void pqc_kernel(
    const float* __restrict__ x,     // (256, 28)
    const float* __restrict__ psq,   // (3, 2, 14, 3)
    const float* __restrict__ p2q,   // (3, 196)
    const float* __restrict__ penc,  // (3, 196)
    const float* __restrict__ pcl,   // (14,)
    float* __restrict__ out)         // (256,)
{
    __shared__ __align__(16) float2 s_amp[DIM_];   // 128 KiB state
    __shared__ float4 s_U4[4][NQ_];                // merged gate sets: (u00,u01); SU(2) derives rest
    __shared__ float2 s_C0[2][128];                // diag cis (layers 0,1; low 7 xor-bits)
    __shared__ float2 s_C1[2][64];                 // diag cis (layers 0,1; high bits, -S/2 folded)
    __shared__ float2 s_WE[NQ_][4];                // 2*W_bp*cis(dphi(s)), s=(k_{bp+1}<<1)|k_{bp-1}
    __shared__ float  s_GL[128];                   // gamma Z-weight, low 7 bits
    __shared__ float  s_GH[128];                   // gamma Z-weight, high 7 bits (Cg folded)
    __shared__ float  s_theta[NLAYERS][NPAIR];
    __shared__ float  s_red[16];

    const int n = blockIdx.x;
    const int t = threadIdx.x;

    // ---------- phase 1: theta + merged gate matrices ----------
    if (t < NLAYERS * NPAIR) {
        int l = t / NPAIR, p = t - l * NPAIR;
        const float* xr = x + n * 28;
        float feat = xr[2*p] * xr[2*p+2] + xr[2*p+1] * xr[2*p+3];
        int pf = 15 * p + 1;
        s_theta[l][p] = p2q[l*196 + pf] + penc[l*196 + pf] * feat;
    } else if (t >= 64 && t < 64 + 4 * NQ_) {
        int j = t - 64;
        int set = j / NQ_;
        int q = j - set * NQ_;
        auto build = [&](int l, int s, float2 Uo[4]) {
            const float* a = psq + ((l * 2 + s) * NQ_ + q) * 3;
            float phi = a[0], th = a[1], om = a[2];
            float sh, ch; sincosf(0.5f * th, &sh, &ch);
            float sa, ca; sincosf(0.5f * (phi + om), &sa, &ca);
            float sb, cb; sincosf(0.5f * (phi - om), &sb, &cb);
            Uo[0] = make_float2( ch * ca, -ch * sa);
            Uo[1] = make_float2(-sh * cb, -sh * sb);
            Uo[2] = make_float2( sh * cb, -sh * sb);
            Uo[3] = make_float2( ch * ca,  ch * sa);
        };
        float2 M[2];
        if (set == 0) {
            float2 T[4]; build(0, 0, T); M[0] = T[0]; M[1] = T[1];
        } else if (set == 3) {
            float2 T[4]; build(2, 1, T); M[0] = T[0]; M[1] = T[1];
        } else {
            float2 A[4], Bm[4];
            build(set, 0, A);        // second
            build(set - 1, 1, Bm);   // first
            M[0].x = A[0].x*Bm[0].x - A[0].y*Bm[0].y + A[1].x*Bm[2].x - A[1].y*Bm[2].y;
            M[0].y = A[0].x*Bm[0].y + A[0].y*Bm[0].x + A[1].x*Bm[2].y + A[1].y*Bm[2].x;
            M[1].x = A[0].x*Bm[1].x - A[0].y*Bm[1].y + A[1].x*Bm[3].x - A[1].y*Bm[3].y;
            M[1].y = A[0].x*Bm[1].y + A[0].y*Bm[1].x + A[1].x*Bm[3].y + A[1].y*Bm[3].x;
        }
        s_U4[set][q] = make_float4(M[0].x, M[0].y, M[1].x, M[1].y);
    }
    __syncthreads();

    // ---------- phase 2: diag cis tables + observable tables ----------
    if (t < 256) {
        int l = t >> 7, i = t & 127;
        float v = 0.0f;
        #pragma unroll
        for (int b = 0; b < 7; ++b)
            if ((i >> b) & 1) v += s_theta[l][12 - b];
        float sn, cs; sincosf(v, &sn, &cs);
        s_C0[l][i] = make_float2(cs, sn);
    } else if (t < 384) {
        int j = t - 256;
        int l = j >> 6, h = j & 63;
        float S = 0.0f;
        #pragma unroll
        for (int p = 0; p < NPAIR; ++p) S += s_theta[l][p];
        float v = -0.5f * S;
        #pragma unroll
        for (int b = 7; b < 13; ++b)
            if ((h >> (b - 7)) & 1) v += s_theta[l][12 - b];
        float sn, cs; sincosf(v, &sn, &cs);
        s_C1[l][h] = make_float2(cs, sn);
    } else if (t < 440) {
        // WE[bp][s] = 2 * W_bp * cis(dphi)
        int idx = t - 384, bp = idx >> 2, s = idx & 3;
        int q = 13 - bp;
        float4 uu = s_U4[3][q];
        float2 v00 = make_float2(uu.x, uu.y), v01 = make_float2(uu.z, uu.w);
        float2 v10 = make_float2(-uu.z, uu.w), v11 = make_float2(uu.x, -uu.y);
        float cz = pcl[q], cx = pcl[bp];
        float t1x = (v00.x*v01.x + v00.y*v01.y) - (v10.x*v11.x + v10.y*v11.y);
        float t1y = (v00.x*v01.y - v00.y*v01.x) - (v10.x*v11.y - v10.y*v11.x);
        float t2x = (v00.x*v11.x + v00.y*v11.y) + (v10.x*v01.x + v10.y*v01.y);
        float t2y = (v00.x*v11.y - v00.y*v11.x) + (v10.x*v01.y - v10.y*v01.x);
        float Wx = cz*t1x + cx*t2x, Wy = cz*t1y + cx*t2y;
        float tha = (bp <= 12) ? s_theta[2][12 - bp] : 0.f;
        float thb = (bp >= 1)  ? s_theta[2][13 - bp] : 0.f;
        float dphi = tha * (1.f - 2.f*((s >> 1) & 1)) + thb * (1.f - 2.f*(s & 1));
        float sn, cs; sincosf(dphi, &sn, &cs);
        s_WE[bp][s] = make_float2(2.f*(Wx*cs - Wy*sn), 2.f*(Wx*sn + Wy*cs));
    } else if (t >= 464 && t < 592) {
        // GL[i] = sum_{b<7, bit set} gamma_b
        int i = t - 464;
        float v = 0.f;
        #pragma unroll
        for (int b = 0; b < 7; ++b)
            if ((i >> b) & 1) {
                int q = 13 - b;
                float4 uu = s_U4[3][q];
                float2 v00 = make_float2(uu.x, uu.y), v10 = make_float2(-uu.z, uu.w);
                v += pcl[q] * ((v00.x*v00.x + v00.y*v00.y) - (v10.x*v10.x + v10.y*v10.y))
                   + 2.f*pcl[b] * (v00.x*v10.x + v00.y*v10.y);
            }
        s_GL[i] = v;
    } else if (t >= 592 && t < 720) {
        // GH[h] = sum_{b<7} gamma_b + sum_{b>=7} gamma_b * (1-2*bit)
        int h = t - 592;
        float v = 0.f;
        #pragma unroll
        for (int b = 0; b < 14; ++b) {
            int q = 13 - b;
            float4 uu = s_U4[3][q];
            float2 v00 = make_float2(uu.x, uu.y), v10 = make_float2(-uu.z, uu.w);
            float g = pcl[q] * ((v00.x*v00.x + v00.y*v00.y) - (v10.x*v10.x + v10.y*v10.y))
                    + 2.f*pcl[b] * (v00.x*v10.x + v00.y*v10.y);
            v += (b >= 7 && ((h >> (b - 7)) & 1)) ? -g : g;
        }
        s_GH[h] = v;
    }
    __syncthreads();

    float2 a[16];
    float acc = 0.0f;

    // ---- layouts A(bits0-3), B(4-7), C(8-11), D(12,13,0,1), E(2,3,7,11) — round-6 SW forms ----
#define LOAD_A() do { _Pragma("unroll") for (int c = 0; c < 8; ++c) { \
        int p = SW((t << 4) | (2*c)); \
        float4 v = *(const float4*)&s_amp[p]; \
        a[2*c] = make_float2(v.x, v.y); a[2*c+1] = make_float2(v.z, v.w); } } while (0)
#define STORE_A() do { _Pragma("unroll") for (int c = 0; c < 8; ++c) { \
        int p = SW((t << 4) | (2*c)); \
        *(float4*)&s_amp[p] = make_float4(a[2*c].x, a[2*c].y, a[2*c+1].x, a[2*c+1].y); } } while (0)
#define LOAD_B() do { int bb = ((t >> 4) << 8) | (t & 15); _Pragma("unroll") \
        for (int j = 0; j < 16; ++j) a[j] = s_amp[SW(bb | (j << 4))]; } while (0)
#define STORE_B() do { int bb = ((t >> 4) << 8) | (t & 15); _Pragma("unroll") \
        for (int j = 0; j < 16; ++j) s_amp[SW(bb | (j << 4))] = a[j]; } while (0)
#define LOAD_C() do { int bc = ((t >> 8) << 12) | (t & 255); _Pragma("unroll") \
        for (int j = 0; j < 16; ++j) a[j] = s_amp[SW(bc | (j << 8))]; } while (0)
#define STORE_C() do { int bc = ((t >> 8) << 12) | (t & 255); _Pragma("unroll") \
        for (int j = 0; j < 16; ++j) s_amp[SW(bc | (j << 8))] = a[j]; } while (0)
#define LOAD_D() do { _Pragma("unroll") for (int jh = 0; jh < 4; ++jh) \
        _Pragma("unroll") for (int c = 0; c < 2; ++c) { \
        int p = SW((jh << 12) | (t << 2) | (2*c)); \
        float4 v = *(const float4*)&s_amp[p]; \
        a[jh*4+2*c] = make_float2(v.x, v.y); a[jh*4+2*c+1] = make_float2(v.z, v.w); } } while (0)
#define STORE_D() do { _Pragma("unroll") for (int jh = 0; jh < 4; ++jh) \
        _Pragma("unroll") for (int c = 0; c < 2; ++c) { \
        int p = SW((jh << 12) | (t << 2) | (2*c)); \
        *(float4*)&s_amp[p] = make_float4(a[jh*4+2*c].x, a[jh*4+2*c].y, a[jh*4+2*c+1].x, a[jh*4+2*c+1].y); } } while (0)

    // ---- P1 (D: bits 12,13,0,1): analytic set0 state, diag0, set1 bits 12,13 ----
    {
        {
            float2 F = make_float2(1.f, 0.f);
            #pragma unroll
            for (int bp = 2; bp < 12; ++bp) {
                int b = (t >> (bp - 2)) & 1;
                float4 uu = s_U4[0][13 - bp];
                float2 f = b ? make_float2(-uu.z, uu.w) : make_float2(uu.x, uu.y);
                F = cmul(F, f);
            }
            float4 u13 = s_U4[0][13], u12 = s_U4[0][12];
            float4 u1q = s_U4[0][1],  u0q = s_U4[0][0];
            float2 c13[2] = { make_float2(u13.x, u13.y), make_float2(-u13.z, u13.w) };
            float2 c12[2] = { make_float2(u12.x, u12.y), make_float2(-u12.z, u12.w) };
            float2 c1q[2] = { make_float2(u1q.x, u1q.y), make_float2(-u1q.z, u1q.w) };
            float2 c0q[2] = { make_float2(u0q.x, u0q.y), make_float2(-u0q.z, u0q.w) };
            float2 g01[4], g23[4];
            #pragma unroll
            for (int j1 = 0; j1 < 2; ++j1)
                #pragma unroll
                for (int j0 = 0; j0 < 2; ++j0)
                    g01[(j1 << 1) | j0] = cmul(c13[j0], c12[j1]);
            #pragma unroll
            for (int j3 = 0; j3 < 2; ++j3)
                #pragma unroll
                for (int j2 = 0; j2 < 2; ++j2)
                    g23[(j3 << 1) | j2] = cmul(c1q[j2], c0q[j3]);
            float2 Fg[4];
            #pragma unroll
            for (int jl = 0; jl < 4; ++jl) Fg[jl] = cmul(F, g01[jl]);
            #pragma unroll
            for (int j = 0; j < 16; ++j) a[j] = cmul(Fg[j & 3], g23[j >> 2]);
        }
        {   // diag0, hoisted: C0 by c=j&3 (4 vals), C1 by jh=j>>2 (4 vals)
            float2 c0v[4], c1v[4];
            int tb = t << 2;
            #pragma unroll
            for (int c = 0; c < 4; ++c) { int kc = tb | c; int mc = kc ^ (kc >> 1); c0v[c] = s_C0[0][mc & 127]; }
            #pragma unroll
            for (int jh = 0; jh < 4; ++jh) { int kh = (jh << 12) | tb; int mh = kh ^ (kh >> 1); c1v[jh] = s_C1[0][(mh >> 7) & 63]; }
            #pragma unroll
            for (int j = 0; j < 16; ++j) a[j] = cmul(a[j], cmul(c0v[j & 3], c1v[j >> 2]));
        }
        GATE_BIT(2, 1, 1);   // bit12 -> qubit 1
        GATE_BIT(3, 1, 0);   // bit13 -> qubit 0
        STORE_D();
    }
    __syncthreads();

    // ---- P2 (C): set1 bits 8-11 ----
    LOAD_C();
    GATE_BIT(0, 1, 5); GATE_BIT(1, 1, 4);
    GATE_BIT(2, 1, 3); GATE_BIT(3, 1, 2);
    STORE_C();
    __syncthreads();

    // ---- P3 (B): set1 bits 4-7 ----
    LOAD_B();
    GATE_BIT(0, 1, 9); GATE_BIT(1, 1, 8);
    GATE_BIT(2, 1, 7); GATE_BIT(3, 1, 6);
    STORE_B();
    __syncthreads();

    // ---- P4 (A): set1 bits 0-3, diag1, set2 bits 0-3, measure X 0-2 ----
    {
        LOAD_A();
        GATE_BIT(0, 1, 13); GATE_BIT(1, 1, 12);
        GATE_BIT(2, 1, 11); GATE_BIT(3, 1, 10);
        {   // diag1: C1 uniform per thread, C0 per j (round-6 form)
            int tb = t << 4; int mT = tb ^ (tb >> 1);
            float2 c1u = s_C1[1][(mT >> 7) & 63];
            #pragma unroll
            for (int j = 0; j < 16; ++j) {
                int kj = tb | j; int mj = kj ^ (kj >> 1);
                a[j] = cmul(a[j], cmul(s_C0[1][mj & 127], c1u));
            }
        }
        GATE_BIT(0, 2, 13); GATE_BIT(1, 2, 12);
        GATE_BIT(2, 2, 11); GATE_BIT(3, 2, 10);
        {
            float2 w0a = s_WE[0][0], w0b = s_WE[0][2];
            MEASW(0, (((j >> 1) & 1) ? w0b : w0a));
        }
        {
            float2 wv0 = s_WE[1][0], wv1 = s_WE[1][1], wv2 = s_WE[1][2], wv3 = s_WE[1][3];
            MEASW(1, (((j >> 2) & 1) ? ((j & 1) ? wv3 : wv2) : ((j & 1) ? wv1 : wv0)));
        }
        {
            float2 wv0 = s_WE[2][0], wv1 = s_WE[2][1], wv2 = s_WE[2][2], wv3 = s_WE[2][3];
            MEASW(2, (((j >> 3) & 1) ? (((j >> 1) & 1) ? wv3 : wv2) : (((j >> 1) & 1) ? wv1 : wv0)));
        }
        STORE_A();
    }
    __syncthreads();

    // ---- P5 (B): set2 bits 4-7, measure X 4-6 ----
    {
        LOAD_B();
        GATE_BIT(0, 2, 9); GATE_BIT(1, 2, 8);
        GATE_BIT(2, 2, 7); GATE_BIT(3, 2, 6);
        {
            int nlo = (t >> 3) & 1;
            float2 wa = s_WE[4][nlo], wb = s_WE[4][2 | nlo];
            MEASW(0, (((j >> 1) & 1) ? wb : wa));
        }
        {
            float2 wv0 = s_WE[5][0], wv1 = s_WE[5][1], wv2 = s_WE[5][2], wv3 = s_WE[5][3];
            MEASW(1, (((j >> 2) & 1) ? ((j & 1) ? wv3 : wv2) : ((j & 1) ? wv1 : wv0)));
        }
        {
            float2 wv0 = s_WE[6][0], wv1 = s_WE[6][1], wv2 = s_WE[6][2], wv3 = s_WE[6][3];
            MEASW(2, (((j >> 3) & 1) ? (((j >> 1) & 1) ? wv3 : wv2) : (((j >> 1) & 1) ? wv1 : wv0)));
        }
        STORE_B();
    }
    __syncthreads();

    // ---- P6 (C): set2 bits 8-11, measure X 8-10 ----
    {
        LOAD_C();
        GATE_BIT(0, 2, 5); GATE_BIT(1, 2, 4);
        GATE_BIT(2, 2, 3); GATE_BIT(3, 2, 2);
        {
            int nlo = (t >> 7) & 1;
            float2 wa = s_WE[8][nlo], wb = s_WE[8][2 | nlo];
            MEASW(0, (((j >> 1) & 1) ? wb : wa));
        }
        {
            float2 wv0 = s_WE[9][0], wv1 = s_WE[9][1], wv2 = s_WE[9][2], wv3 = s_WE[9][3];
            MEASW(1, (((j >> 2) & 1) ? ((j & 1) ? wv3 : wv2) : ((j & 1) ? wv1 : wv0)));
        }
        {
            float2 wv0 = s_WE[10][0], wv1 = s_WE[10][1], wv2 = s_WE[10][2], wv3 = s_WE[10][3];
            MEASW(2, (((j >> 3) & 1) ? (((j >> 1) & 1) ? wv3 : wv2) : (((j >> 1) & 1) ? wv1 : wv0)));
        }
        STORE_C();
    }
    __syncthreads();

    // ---- P7 (D): set2 bits 12,13, measure X 12,13 ----
    {
        LOAD_D();
        GATE_BIT(2, 2, 1); GATE_BIT(3, 2, 0);
        {
            int nlo = (t >> 9) & 1;
            float2 wa = s_WE[12][nlo], wb = s_WE[12][2 | nlo];
            MEASW(2, (((j >> 3) & 1) ? wb : wa));
        }
        {
            float2 wa = s_WE[13][0], wb = s_WE[13][1];
            MEASW(3, (((j >> 2) & 1) ? wb : wa));
        }
        STORE_D();
    }
    __syncthreads();

    // ---- P8 (E: bits 2,3,7,11): measure X 3,7,11 + WZ sweep (load only) ----
    {
        int kb = (t & 3) | (((t >> 2) & 7) << 4) | (((t >> 5) & 7) << 8) | (((t >> 8) & 3) << 12);
        int exor = ((t >> 2) & 7) << 1;
        #pragma unroll
        for (int j = 0; j < 16; ++j) {
            int k = kb | ((j & 3) << 2) | (((j >> 2) & 1) << 7) | (((j >> 3) & 1) << 11);
            a[j] = s_amp[k ^ exor];
        }
        // WZ: hoist 4 GH (by j>>2) and 4 GL (by j&3)
        {
            float ghv[4], glv[4];
            int khb = kb >> 7, klb = kb & 127;
            #pragma unroll
            for (int q2 = 0; q2 < 4; ++q2) ghv[q2] = s_GH[khb | (q2 & 1) | ((q2 >> 1) << 4)];
            #pragma unroll
            for (int c = 0; c < 4; ++c) glv[c] = s_GL[klb | (c << 2)];
            float wzs = 0.f;
            #pragma unroll
            for (int j = 0; j < 16; ++j) {
                float prj = a[j].x*a[j].x + a[j].y*a[j].y;
                wzs += prj * (ghv[j >> 2] - 2.0f * glv[j & 3]);
            }
            acc += wzs;
        }
        {
            int nh = (t >> 2) & 1;
            float2 wa = s_WE[3][nh << 1], wb = s_WE[3][(nh << 1) | 1];
            MEASW(1, ((j & 1) ? wb : wa));
        }
        {
            float2 w7 = s_WE[7][(((t >> 5) & 1) << 1) | ((t >> 4) & 1)];
            MEASW(2, w7);
        }
        {
            float2 w11 = s_WE[11][(((t >> 8) & 1) << 1) | ((t >> 7) & 1)];
            MEASW(3, w11);
        }
    }

    // ---- block reduction ----
    #pragma unroll
    for (int off = 32; off > 0; off >>= 1)
        acc += __shfl_down(acc, off);
    if ((t & 63) == 0) s_red[t >> 6] = acc;
    __syncthreads();
    if (t == 0) {
        float s = 0.0f;
        #pragma unroll
        for (int w = 0; w < 16; ++w) s += s_red[w];
        out[n] = s;
    }
}

extern "C" void kernel_launch(void* const* d_in, const int* in_sizes, int n_in,
                              void* d_out, int out_size, void* d_ws, size_t ws_size,
                              hipStream_t stream) {
    const float* x    = (const float*)d_in[0];
    const float* psq  = (const float*)d_in[1];
    const float* p2q  = (const float*)d_in[2];
    const float* penc = (const float*)d_in[3];
    const float* pcl  = (const float*)d_in[4];
    float* out = (float*)d_out;
    pqc_kernel<<<NB, NT, 0, stream>>>(x, psq, p2q, penc, pcl, out);
}

// Round 10
// 36.607 us; speedup vs baseline: 1.3429x; 1.3429x over previous
//
#include <hip/hip_runtime.h>
#include <math.h>

#define NQ_     14
#define DIM_    16384
#define NB      256
#define NLAYERS 3
#define NPAIR   13
#define NT      1024

// LDS swizzle: XOR bits 1-3 of the float2 index with bits 4-6.
#define SW(k) ((k) ^ ((((k) >> 4) & 7) << 1))

__device__ __forceinline__ float2 cmul(float2 a, float2 b) {
    return make_float2(a.x*b.x - a.y*b.y, a.x*b.y + a.y*b.x);
}

// SU(2) gate: u10 = -conj(u01), u11 = conj(u00) derived via free neg modifiers.
__device__ __forceinline__ void g2s(float2& a0, float2& a1, float2 u00, float2 u01) {
    float2 b0, b1;
    b0.x =  u00.x*a0.x - u00.y*a0.y + u01.x*a1.x - u01.y*a1.y;
    b0.y =  u00.x*a0.y + u00.y*a0.x + u01.x*a1.y + u01.y*a1.x;
    b1.x = -u01.x*a0.x - u01.y*a0.y + u00.x*a1.x + u00.y*a1.y;
    b1.y = -u01.x*a0.y + u01.y*a0.x + u00.x*a1.y - u00.y*a1.x;
    a0 = b0; a1 = b1;
}

// apply gate across register bit RB; gate fetched as ONE float4 from s_U4
#define GATE_BIT(RB, SET, Q) do { \
    float4 uu = s_U4[SET][Q]; \
    float2 u00 = make_float2(uu.x, uu.y), u01 = make_float2(uu.z, uu.w); \
    _Pragma("unroll") \
    for (int j = 0; j < 16; ++j) \
        if (!((j >> (RB)) & 1)) g2s(a[j], a[j | (1 << (RB))], u00, u01); \
} while (0)

    // Measure bit bp at register bit RB: Z part (gamma) + phase-corrected X/Y part (WE).
    // |a|^2 computed inline per pair (round-6 form: no pr[] array, per-pair LDS w read).
#define MEAS(BP, RB, NHI, NLO) do { \
    float g = s_G[BP]; float zs = 0.f, xr = 0.f; \
    const float2* WEp = s_WE[BP]; \
    _Pragma("unroll") for (int j = 0; j < 16; ++j) { \
        if (!((j >> (RB)) & 1)) { \
            int j1 = j | (1 << (RB)); \
            float cr = a[j].x*a[j1].x + a[j].y*a[j1].y; \
            float ci = a[j].x*a[j1].y - a[j].y*a[j1].x; \
            float2 w = WEp[((NHI) << 1) | (NLO)]; \
            xr += w.x * cr - w.y * ci; \
            zs += (a[j].x*a[j].x + a[j].y*a[j].y) - (a[j1].x*a[j1].x + a[j1].y*a[j1].y); \
        } } \
    acc += g * zs + xr; \
} while (0)

__global__ __launch_bounds__(NT, 4) void pqc_kernel(
    const float* __restrict__ x,     // (256, 28)
    const float* __restrict__ psq,   // (3, 2, 14, 3)
    const float* __restrict__ p2q,   // (3, 196)
    const float* __restrict__ penc,  // (3, 196)
    const float* __restrict__ pcl,   // (14,)
    float* __restrict__ out)         // (256,)
{
    __shared__ __align__(16) float2 s_amp[DIM_];   // 128 KiB state
    __shared__ float4 s_U4[4][NQ_];                // merged gate sets: (u00,u01); SU(2) derives rest
    __shared__ float2 s_C0[2][128];                // diag cis (layers 0,1; low 7 xor-bits)
    __shared__ float2 s_C1[2][64];                 // diag cis (layers 0,1; high bits, -S/2 folded)
    __shared__ float2 s_WE[NQ_][4];                // 2*W_bp*cis(dphi(s)), s=(k_{bp+1}<<1)|k_{bp-1}
    __shared__ float  s_G[NQ_];                    // gamma_bp (Z coefficient after set3 rotation)
    __shared__ float  s_theta[NLAYERS][NPAIR];
    __shared__ float  s_red[16];

    const int n = blockIdx.x;
    const int t = threadIdx.x;

    // ---------- phase 1: theta + merged gate matrices ----------
    if (t < NLAYERS * NPAIR) {
        int l = t / NPAIR, p = t - l * NPAIR;
        const float* xr = x + n * 28;
        float feat = xr[2*p] * xr[2*p+2] + xr[2*p+1] * xr[2*p+3];
        int pf = 15 * p + 1;
        s_theta[l][p] = p2q[l*196 + pf] + penc[l*196 + pf] * feat;
    } else if (t >= 64 && t < 64 + 4 * NQ_) {
        // set0 = U0(L0); set1 = U0(L1)*U1(L0); set2 = U0(L2)*U1(L1); set3 = U1(L2)
        int j = t - 64;
        int set = j / NQ_;
        int q = j - set * NQ_;
        auto build = [&](int l, int s, float2 Uo[4]) {
            const float* a = psq + ((l * 2 + s) * NQ_ + q) * 3;
            float phi = a[0], th = a[1], om = a[2];
            float sh, ch; sincosf(0.5f * th, &sh, &ch);
            float sa, ca; sincosf(0.5f * (phi + om), &sa, &ca);
            float sb, cb; sincosf(0.5f * (phi - om), &sb, &cb);
            Uo[0] = make_float2( ch * ca, -ch * sa);
            Uo[1] = make_float2(-sh * cb, -sh * sb);
            Uo[2] = make_float2( sh * cb, -sh * sb);
            Uo[3] = make_float2( ch * ca,  ch * sa);
        };
        float2 M0, M1;
        if (set == 0) {
            float2 T[4]; build(0, 0, T); M0 = T[0]; M1 = T[1];
        } else if (set == 3) {
            float2 T[4]; build(2, 1, T); M0 = T[0]; M1 = T[1];
        } else {
            float2 A[4], Bm[4];
            build(set, 0, A);        // second
            build(set - 1, 1, Bm);   // first
            M0.x = A[0].x*Bm[0].x - A[0].y*Bm[0].y + A[1].x*Bm[2].x - A[1].y*Bm[2].y;
            M0.y = A[0].x*Bm[0].y + A[0].y*Bm[0].x + A[1].x*Bm[2].y + A[1].y*Bm[2].x;
            M1.x = A[0].x*Bm[1].x - A[0].y*Bm[1].y + A[1].x*Bm[3].x - A[1].y*Bm[3].y;
            M1.y = A[0].x*Bm[1].y + A[0].y*Bm[1].x + A[1].x*Bm[3].y + A[1].y*Bm[3].x;
        }
        s_U4[set][q] = make_float4(M0.x, M0.y, M1.x, M1.y);
    }
    __syncthreads();

    // ---------- phase 2: diag cis tables + observable tables ----------
    if (t < 256) {
        int l = t >> 7, i = t & 127;
        float v = 0.0f;
        #pragma unroll
        for (int b = 0; b < 7; ++b)
            if ((i >> b) & 1) v += s_theta[l][12 - b];
        float sn, cs; sincosf(v, &sn, &cs);
        s_C0[l][i] = make_float2(cs, sn);
    } else if (t < 384) {
        int j = t - 256;
        int l = j >> 6, h = j & 63;
        float S = 0.0f;
        #pragma unroll
        for (int p = 0; p < NPAIR; ++p) S += s_theta[l][p];
        float v = -0.5f * S;
        #pragma unroll
        for (int b = 7; b < 13; ++b)
            if ((h >> (b - 7)) & 1) v += s_theta[l][12 - b];
        float sn, cs; sincosf(v, &sn, &cs);
        s_C1[l][h] = make_float2(cs, sn);
    } else if (t < 440) {
        // WE[bp][s] = 2 * W_bp * cis(dphi); rows of set3 derived from SU(2)
        int idx = t - 384, bp = idx >> 2, s = idx & 3;
        int q = 13 - bp;
        float4 uu = s_U4[3][q];
        float2 v00 = make_float2(uu.x, uu.y), v01 = make_float2(uu.z, uu.w);
        float2 v10 = make_float2(-uu.z, uu.w), v11 = make_float2(uu.x, -uu.y);
        float cz = pcl[q], cx = pcl[bp];
        float t1x = (v00.x*v01.x + v00.y*v01.y) - (v10.x*v11.x + v10.y*v11.y);
        float t1y = (v00.x*v01.y - v00.y*v01.x) - (v10.x*v11.y - v10.y*v11.x);
        float t2x = (v00.x*v11.x + v00.y*v11.y) + (v10.x*v01.x + v10.y*v01.y);
        float t2y = (v00.x*v11.y - v00.y*v11.x) + (v10.x*v01.y - v10.y*v01.x);
        float Wx = cz*t1x + cx*t2x, Wy = cz*t1y + cx*t2y;
        float tha = (bp <= 12) ? s_theta[2][12 - bp] : 0.f;
        float thb = (bp >= 1)  ? s_theta[2][13 - bp] : 0.f;
        float dphi = tha * (1.f - 2.f*((s >> 1) & 1)) + thb * (1.f - 2.f*(s & 1));
        float sn, cs; sincosf(dphi, &sn, &cs);
        s_WE[bp][s] = make_float2(2.f*(Wx*cs - Wy*sn), 2.f*(Wx*sn + Wy*cs));
    } else if (t >= 448 && t < 462) {
        int bp = t - 448, q = 13 - bp;
        float4 uu = s_U4[3][q];
        float2 v00 = make_float2(uu.x, uu.y), v10 = make_float2(-uu.z, uu.w);
        float cz = pcl[q], cx = pcl[bp];
        s_G[bp] = cz * ((v00.x*v00.x + v00.y*v00.y) - (v10.x*v10.x + v10.y*v10.y))
                + 2.f*cx * (v00.x*v10.x + v00.y*v10.y);
    }
    __syncthreads();

    float2 a[16];
    float acc = 0.0f;

    // ---- layouts A(bits0-3), B(4-7), C(8-11), D(12,13,0,1), E(2,3,7,11) ----
#define LOAD_A() do { _Pragma("unroll") for (int c = 0; c < 8; ++c) { \
        int p = SW((t << 4) | (2*c)); \
        float4 v = *(const float4*)&s_amp[p]; \
        a[2*c] = make_float2(v.x, v.y); a[2*c+1] = make_float2(v.z, v.w); } } while (0)
#define STORE_A() do { _Pragma("unroll") for (int c = 0; c < 8; ++c) { \
        int p = SW((t << 4) | (2*c)); \
        *(float4*)&s_amp[p] = make_float4(a[2*c].x, a[2*c].y, a[2*c+1].x, a[2*c+1].y); } } while (0)
#define LOAD_B() do { int bb = ((t >> 4) << 8) | (t & 15); _Pragma("unroll") \
        for (int j = 0; j < 16; ++j) a[j] = s_amp[SW(bb | (j << 4))]; } while (0)
#define STORE_B() do { int bb = ((t >> 4) << 8) | (t & 15); _Pragma("unroll") \
        for (int j = 0; j < 16; ++j) s_amp[SW(bb | (j << 4))] = a[j]; } while (0)
#define LOAD_C() do { int bc = ((t >> 8) << 12) | (t & 255); _Pragma("unroll") \
        for (int j = 0; j < 16; ++j) a[j] = s_amp[SW(bc | (j << 8))]; } while (0)
#define STORE_C() do { int bc = ((t >> 8) << 12) | (t & 255); _Pragma("unroll") \
        for (int j = 0; j < 16; ++j) s_amp[SW(bc | (j << 8))] = a[j]; } while (0)
#define LOAD_D() do { _Pragma("unroll") for (int jh = 0; jh < 4; ++jh) \
        _Pragma("unroll") for (int c = 0; c < 2; ++c) { \
        int p = SW((jh << 12) | (t << 2) | (2*c)); \
        float4 v = *(const float4*)&s_amp[p]; \
        a[jh*4+2*c] = make_float2(v.x, v.y); a[jh*4+2*c+1] = make_float2(v.z, v.w); } } while (0)
#define STORE_D() do { _Pragma("unroll") for (int jh = 0; jh < 4; ++jh) \
        _Pragma("unroll") for (int c = 0; c < 2; ++c) { \
        int p = SW((jh << 12) | (t << 2) | (2*c)); \
        *(float4*)&s_amp[p] = make_float4(a[jh*4+2*c].x, a[jh*4+2*c].y, a[jh*4+2*c+1].x, a[jh*4+2*c+1].y); } } while (0)

    // ---- P1 (D: bits 12,13,0,1): analytic set0 state, diag0, set1 bits 12,13 ----
    {
        float2 F = make_float2(1.f, 0.f);
        #pragma unroll
        for (int bp = 2; bp < 12; ++bp) {
            int b = (t >> (bp - 2)) & 1;
            float4 uu = s_U4[0][13 - bp];
            float2 f = b ? make_float2(-uu.z, uu.w) : make_float2(uu.x, uu.y); // col-0
            F = cmul(F, f);
        }
        float4 u13 = s_U4[0][13], u12 = s_U4[0][12];
        float4 u1q = s_U4[0][1],  u0q = s_U4[0][0];
        float2 c13[2] = { make_float2(u13.x, u13.y), make_float2(-u13.z, u13.w) };
        float2 c12[2] = { make_float2(u12.x, u12.y), make_float2(-u12.z, u12.w) };
        float2 c1q[2] = { make_float2(u1q.x, u1q.y), make_float2(-u1q.z, u1q.w) };
        float2 c0q[2] = { make_float2(u0q.x, u0q.y), make_float2(-u0q.z, u0q.w) };
        float2 g01[4], g23[4];
        #pragma unroll
        for (int j1 = 0; j1 < 2; ++j1)
            #pragma unroll
            for (int j0 = 0; j0 < 2; ++j0)
                g01[(j1 << 1) | j0] = cmul(c13[j0], c12[j1]);
        #pragma unroll
        for (int j3 = 0; j3 < 2; ++j3)
            #pragma unroll
            for (int j2 = 0; j2 < 2; ++j2)
                g23[(j3 << 1) | j2] = cmul(c1q[j2], c0q[j3]);
        float2 Fg[4];
        #pragma unroll
        for (int jl = 0; jl < 4; ++jl) Fg[jl] = cmul(F, g01[jl]);
        #pragma unroll
        for (int j = 0; j < 16; ++j) a[j] = cmul(Fg[j & 3], g23[j >> 2]);
    }
    {   // diag0, hoisted: C0 by c=j&3 (4 vals), C1 by jh=j>>2 (4 vals)
        float2 c0v[4], c1v[4];
        int tb = t << 2;
        #pragma unroll
        for (int c = 0; c < 4; ++c) { int kc = tb | c; int mc = kc ^ (kc >> 1); c0v[c] = s_C0[0][mc & 127]; }
        #pragma unroll
        for (int jh = 0; jh < 4; ++jh) { int kh = (jh << 12) | tb; int mh = kh ^ (kh >> 1); c1v[jh] = s_C1[0][(mh >> 7) & 63]; }
        #pragma unroll
        for (int j = 0; j < 16; ++j) a[j] = cmul(a[j], cmul(c0v[j & 3], c1v[j >> 2]));
    }
    GATE_BIT(2, 1, 1);   // bit12 -> qubit 1
    GATE_BIT(3, 1, 0);   // bit13 -> qubit 0
    STORE_D(); __syncthreads();

    // ---- P2 (C): set1 bits 8-11 ----
    LOAD_C();
    GATE_BIT(0, 1, 5); GATE_BIT(1, 1, 4);
    GATE_BIT(2, 1, 3); GATE_BIT(3, 1, 2);
    STORE_C(); __syncthreads();

    // ---- P3 (B): set1 bits 4-7 ----
    LOAD_B();
    GATE_BIT(0, 1, 9); GATE_BIT(1, 1, 8);
    GATE_BIT(2, 1, 7); GATE_BIT(3, 1, 6);
    STORE_B(); __syncthreads();

    // ---- P4 (A): set1 bits 0-3, diag1, set2 bits 0-3, measure 0-2 ----
    LOAD_A();
    GATE_BIT(0, 1, 13); GATE_BIT(1, 1, 12);
    GATE_BIT(2, 1, 11); GATE_BIT(3, 1, 10);
    {   // diag1: C1 uniform per thread, C0 per j
        int tb = t << 4; int mT = tb ^ (tb >> 1);
        float2 c1u = s_C1[1][(mT >> 7) & 63];
        #pragma unroll
        for (int j = 0; j < 16; ++j) {
            int kj = tb | j; int mj = kj ^ (kj >> 1);
            a[j] = cmul(a[j], cmul(s_C0[1][mj & 127], c1u));
        }
    }
    GATE_BIT(0, 2, 13); GATE_BIT(1, 2, 12);
    GATE_BIT(2, 2, 11); GATE_BIT(3, 2, 10);
    MEAS(0, 0, ((j >> 1) & 1), 0);
    MEAS(1, 1, ((j >> 2) & 1), (j & 1));
    MEAS(2, 2, ((j >> 3) & 1), ((j >> 1) & 1));
    STORE_A(); __syncthreads();

    // ---- P5 (B): set2 bits 4-7, measure 4-6 ----
    LOAD_B();
    GATE_BIT(0, 2, 9); GATE_BIT(1, 2, 8);
    GATE_BIT(2, 2, 7); GATE_BIT(3, 2, 6);
    MEAS(4, 0, ((j >> 1) & 1), ((t >> 3) & 1));
    MEAS(5, 1, ((j >> 2) & 1), (j & 1));
    MEAS(6, 2, ((j >> 3) & 1), ((j >> 1) & 1));
    STORE_B(); __syncthreads();

    // ---- P6 (C): set2 bits 8-11, measure 8-10 ----
    LOAD_C();
    GATE_BIT(0, 2, 5); GATE_BIT(1, 2, 4);
    GATE_BIT(2, 2, 3); GATE_BIT(3, 2, 2);
    MEAS(8, 0, ((j >> 1) & 1), ((t >> 7) & 1));
    MEAS(9, 1, ((j >> 2) & 1), (j & 1));
    MEAS(10, 2, ((j >> 3) & 1), ((j >> 1) & 1));
    STORE_C(); __syncthreads();

    // ---- P7 (D): set2 bits 12,13, measure 12,13 ----
    LOAD_D();
    GATE_BIT(2, 2, 1); GATE_BIT(3, 2, 0);
    MEAS(12, 2, ((j >> 3) & 1), ((t >> 9) & 1));
    MEAS(13, 3, 0, ((j >> 2) & 1));
    STORE_D(); __syncthreads();

    // ---- P8 (E: bits 2,3,7,11): measure 3,7,11 (load only) ----
    {
        int kb = (t & 3) | (((t >> 2) & 7) << 4) | (((t >> 5) & 7) << 8) | (((t >> 8) & 3) << 12);
        int exor = ((t >> 2) & 7) << 1;
        #pragma unroll
        for (int j = 0; j < 16; ++j) {
            int k = kb | ((j & 3) << 2) | (((j >> 2) & 1) << 7) | (((j >> 3) & 1) << 11);
            a[j] = s_amp[k ^ exor];
        }
        MEAS(3,  1, ((t >> 2) & 1), (j & 1));
        MEAS(7,  2, ((t >> 5) & 1), ((t >> 4) & 1));
        MEAS(11, 3, ((t >> 8) & 1), ((t >> 7) & 1));
    }

    // ---- block reduction ----
    #pragma unroll
    for (int off = 32; off > 0; off >>= 1)
        acc += __shfl_down(acc, off);
    if ((t & 63) == 0) s_red[t >> 6] = acc;
    __syncthreads();
    if (t == 0) {
        float s = 0.0f;
        #pragma unroll
        for (int w = 0; w < 16; ++w) s += s_red[w];
        out[n] = s;
    }
}

extern "C" void kernel_launch(void* const* d_in, const int* in_sizes, int n_in,
                              void* d_out, int out_size, void* d_ws, size_t ws_size,
                              hipStream_t stream) {
    const float* x    = (const float*)d_in[0];
    const float* psq  = (const float*)d_in[1];
    const float* p2q  = (const float*)d_in[2];
    const float* penc = (const float*)d_in[3];
    const float* pcl  = (const float*)d_in[4];
    float* out = (float*)d_out;
    pqc_kernel<<<NB, NT, 0, stream>>>(x, psq, p2q, penc, pcl, out);
}

// Round 12
// 34.951 us; speedup vs baseline: 1.4065x; 1.0474x over previous
//
#include <hip/hip_runtime.h>
#include <math.h>

#define NQ_     14
#define DIM_    16384
#define NB      256
#define NLAYERS 3
#define NPAIR   13
#define NT      1024

// LDS swizzle: XOR bits 1-3 of the float2 index with bits 4-6.
#define SW(k) ((k) ^ ((((k) >> 4) & 7) << 1))

__device__ __forceinline__ float2 cmul(float2 a, float2 b) {
    return make_float2(a.x*b.x - a.y*b.y, a.x*b.y + a.y*b.x);
}

// SU(2) gate: u10 = -conj(u01), u11 = conj(u00) derived via free neg modifiers.
__device__ __forceinline__ void g2s(float2& a0, float2& a1, float2 u00, float2 u01) {
    float2 b0, b1;
    b0.x =  u00.x*a0.x - u00.y*a0.y + u01.x*a1.x - u01.y*a1.y;
    b0.y =  u00.x*a0.y + u00.y*a0.x + u01.x*a1.y + u01.y*a1.x;
    b1.x = -u01.x*a0.x - u01.y*a0.y + u00.x*a1.x + u00.y*a1.y;
    b1.y = -u01.x*a0.y + u01.y*a0.x + u00.x*a1.y - u00.y*a1.x;
    a0 = b0; a1 = b1;
}

// Variant gate, register-bit neighbor: variant chosen per-j at COMPILE TIME.
#define GATE_BITVJ(RB, TBL, G, JB) do { \
    float4 uu0 = TBL[G][0], uu1 = TBL[G][1]; \
    _Pragma("unroll") \
    for (int j = 0; j < 16; ++j) \
        if (!((j >> (RB)) & 1)) { \
            float4 uu = ((j >> (JB)) & 1) ? uu1 : uu0; \
            g2s(a[j], a[j | (1 << (RB))], make_float2(uu.x, uu.y), make_float2(uu.z, uu.w)); \
        } \
} while (0)

// Variant gate, wave-uniform neighbor (or N=0 for plain): single indexed load.
#define GATE_BITVU(RB, TBL, G, N) do { \
    float4 uu = TBL[G][N]; \
    float2 u00 = make_float2(uu.x, uu.y), u01 = make_float2(uu.z, uu.w); \
    _Pragma("unroll") \
    for (int j = 0; j < 16; ++j) \
        if (!((j >> (RB)) & 1)) g2s(a[j], a[j | (1 << (RB))], u00, u01); \
} while (0)

    // Measure bit bp at register bit RB: Z part (gamma) + phase-corrected X/Y part (WE).
#define MEAS(BP, RB, NHI, NLO) do { \
    float g = s_G[BP]; float zs = 0.f, xr = 0.f; \
    const float2* WEp = s_WE[BP]; \
    _Pragma("unroll") for (int j = 0; j < 16; ++j) { \
        if (!((j >> (RB)) & 1)) { \
            int j1 = j | (1 << (RB)); \
            float cr = a[j].x*a[j1].x + a[j].y*a[j1].y; \
            float ci = a[j].x*a[j1].y - a[j].y*a[j1].x; \
            float2 w = WEp[((NHI) << 1) | (NLO)]; \
            xr += w.x * cr - w.y * ci; \
            zs += (a[j].x*a[j].x + a[j].y*a[j].y) - (a[j1].x*a[j1].x + a[j1].y*a[j1].y); \
        } } \
    acc += g * zs + xr; \
} while (0)

__global__ __launch_bounds__(NT, 4) void pqc_kernel(
    const float* __restrict__ x,     // (256, 28)
    const float* __restrict__ psq,   // (3, 2, 14, 3)
    const float* __restrict__ p2q,   // (3, 196)
    const float* __restrict__ penc,  // (3, 196)
    const float* __restrict__ pcl,   // (14,)
    float* __restrict__ out)         // (256,)
{
    __shared__ __align__(16) float2 s_amp[DIM_];   // 128 KiB state
    __shared__ float4 s_U4[4][NQ_];                // merged gate sets (u00,u01), SU(2)
    __shared__ float4 s_V1[NQ_][2];                // set1 gates with diag0 pair-factor folded, by bit g
    __shared__ float4 s_V2[NQ_][2];                // set2 gates with diag1 pair-factor folded, by bit g
    __shared__ float2 s_WE[NQ_][4];                // 2*W_bp*cis(dphi(s)), s=(k_{bp+1}<<1)|k_{bp-1}
    __shared__ float  s_G[NQ_];                    // gamma_bp (Z coefficient after set3 rotation)
    __shared__ float  s_theta[NLAYERS][NPAIR];
    __shared__ float  s_red[16];

    const int n = blockIdx.x;
    const int t = threadIdx.x;

    // ---------- phase 1: theta + merged gate matrices ----------
    if (t < NLAYERS * NPAIR) {
        int l = t / NPAIR, p = t - l * NPAIR;
        const float* xr = x + n * 28;
        float feat = xr[2*p] * xr[2*p+2] + xr[2*p+1] * xr[2*p+3];
        int pf = 15 * p + 1;
        s_theta[l][p] = p2q[l*196 + pf] + penc[l*196 + pf] * feat;
    } else if (t >= 64 && t < 64 + 4 * NQ_) {
        // set0 = U0(L0); set1 = U0(L1)*U1(L0); set2 = U0(L2)*U1(L1); set3 = U1(L2)
        int j = t - 64;
        int set = j / NQ_;
        int q = j - set * NQ_;
        auto build = [&](int l, int s, float2 Uo[4]) {
            const float* a = psq + ((l * 2 + s) * NQ_ + q) * 3;
            float phi = a[0], th = a[1], om = a[2];
            float sh, ch; sincosf(0.5f * th, &sh, &ch);
            float sa, ca; sincosf(0.5f * (phi + om), &sa, &ca);
            float sb, cb; sincosf(0.5f * (phi - om), &sb, &cb);
            Uo[0] = make_float2( ch * ca, -ch * sa);
            Uo[1] = make_float2(-sh * cb, -sh * sb);
            Uo[2] = make_float2( sh * cb, -sh * sb);
            Uo[3] = make_float2( ch * ca,  ch * sa);
        };
        float2 M0, M1;
        if (set == 0) {
            float2 T[4]; build(0, 0, T); M0 = T[0]; M1 = T[1];
        } else if (set == 3) {
            float2 T[4]; build(2, 1, T); M0 = T[0]; M1 = T[1];
        } else {
            float2 A[4], Bm[4];
            build(set, 0, A);        // second
            build(set - 1, 1, Bm);   // first
            M0.x = A[0].x*Bm[0].x - A[0].y*Bm[0].y + A[1].x*Bm[2].x - A[1].y*Bm[2].y;
            M0.y = A[0].x*Bm[0].y + A[0].y*Bm[0].x + A[1].x*Bm[2].y + A[1].y*Bm[2].x;
            M1.x = A[0].x*Bm[1].x - A[0].y*Bm[1].y + A[1].x*Bm[3].x - A[1].y*Bm[3].y;
            M1.y = A[0].x*Bm[1].y + A[0].y*Bm[1].x + A[1].x*Bm[3].y + A[1].y*Bm[3].x;
        }
        s_U4[set][q] = make_float4(M0.x, M0.y, M1.x, M1.y);
    }
    __syncthreads();

    // ---------- phase 2: observable tables + diag-folded gate variants ----------
    if (t < 56) {
        // WE[bp][s] = 2 * W_bp * cis(dphi); rows of set3 derived from SU(2)
        int bp = t >> 2, s = t & 3;
        int q = 13 - bp;
        float4 uu = s_U4[3][q];
        float2 v00 = make_float2(uu.x, uu.y), v01 = make_float2(uu.z, uu.w);
        float2 v10 = make_float2(-uu.z, uu.w), v11 = make_float2(uu.x, -uu.y);
        float cz = pcl[q], cx = pcl[bp];
        float t1x = (v00.x*v01.x + v00.y*v01.y) - (v10.x*v11.x + v10.y*v11.y);
        float t1y = (v00.x*v01.y - v00.y*v01.x) - (v10.x*v11.y - v10.y*v11.x);
        float t2x = (v00.x*v11.x + v00.y*v11.y) + (v10.x*v01.x + v10.y*v01.y);
        float t2y = (v00.x*v11.y - v00.y*v11.x) + (v10.x*v01.y - v10.y*v01.x);
        float Wx = cz*t1x + cx*t2x, Wy = cz*t1y + cx*t2y;
        float tha = (bp <= 12) ? s_theta[2][12 - bp] : 0.f;
        float thb = (bp >= 1)  ? s_theta[2][13 - bp] : 0.f;
        float dphi = tha * (1.f - 2.f*((s >> 1) & 1)) + thb * (1.f - 2.f*(s & 1));
        float sn, cs; sincosf(dphi, &sn, &cs);
        s_WE[bp][s] = make_float2(2.f*(Wx*cs - Wy*sn), 2.f*(Wx*sn + Wy*cs));
    } else if (t >= 64 && t < 92) {
        // V1[g][n]: set1 gate on bit g with diag0 pair (g-1,g) folded; n = value of bit g-1.
        // 28 entries: g=0..13, n=0..1. c = cis(-th/2) for n=0, conj for n=1.
        int idx = t - 64, g = idx >> 1, nn = idx & 1;
        float4 uu = s_U4[1][13 - g];
        float th = (g >= 1) ? s_theta[0][13 - g] : 0.f;
        float sn, cs; sincosf(0.5f * th, &sn, &cs);
        float cy = nn ? sn : -sn;
        s_V1[g][nn] = make_float4(uu.x*cs - uu.y*cy, uu.x*cy + uu.y*cs,
                                  uu.z*cs + uu.w*cy, uu.w*cs - uu.z*cy);
    } else if (t >= 128 && t < 156) {
        // V2[g][n]: set2 gate on bit g with diag1 pair (g,g+1) folded; n = value of bit g+1.
        int idx = t - 128, g = idx >> 1, nn = idx & 1;
        float4 uu = s_U4[2][13 - g];
        float th = (g <= 12) ? s_theta[1][12 - g] : 0.f;
        float sn, cs; sincosf(0.5f * th, &sn, &cs);
        float cy = nn ? sn : -sn;
        s_V2[g][nn] = make_float4(uu.x*cs - uu.y*cy, uu.x*cy + uu.y*cs,
                                  uu.z*cs + uu.w*cy, uu.w*cs - uu.z*cy);
    } else if (t >= 192 && t < 206) {
        int bp = t - 192, q = 13 - bp;
        float4 uu = s_U4[3][q];
        float2 v00 = make_float2(uu.x, uu.y), v10 = make_float2(-uu.z, uu.w);
        float cz = pcl[q], cx = pcl[bp];
        s_G[bp] = cz * ((v00.x*v00.x + v00.y*v00.y) - (v10.x*v10.x + v10.y*v10.y))
                + 2.f*cx * (v00.x*v10.x + v00.y*v10.y);
    }
    __syncthreads();

    float2 a[16];
    float acc = 0.0f;

    // ---- layouts A(bits0-3), B(4-7), C(8-11), D(12,13,0,1), E(2,3,7,11) ----
#define LOAD_A() do { _Pragma("unroll") for (int c = 0; c < 8; ++c) { \
        int p = SW((t << 4) | (2*c)); \
        float4 v = *(const float4*)&s_amp[p]; \
        a[2*c] = make_float2(v.x, v.y); a[2*c+1] = make_float2(v.z, v.w); } } while (0)
#define STORE_A() do { _Pragma("unroll") for (int c = 0; c < 8; ++c) { \
        int p = SW((t << 4) | (2*c)); \
        *(float4*)&s_amp[p] = make_float4(a[2*c].x, a[2*c].y, a[2*c+1].x, a[2*c+1].y); } } while (0)
#define LOAD_B() do { int bb = ((t >> 4) << 8) | (t & 15); _Pragma("unroll") \
        for (int j = 0; j < 16; ++j) a[j] = s_amp[SW(bb | (j << 4))]; } while (0)
#define STORE_B() do { int bb = ((t >> 4) << 8) | (t & 15); _Pragma("unroll") \
        for (int j = 0; j < 16; ++j) s_amp[SW(bb | (j << 4))] = a[j]; } while (0)
#define LOAD_C() do { int bc = ((t >> 8) << 12) | (t & 255); _Pragma("unroll") \
        for (int j = 0; j < 16; ++j) a[j] = s_amp[SW(bc | (j << 8))]; } while (0)
#define STORE_C() do { int bc = ((t >> 8) << 12) | (t & 255); _Pragma("unroll") \
        for (int j = 0; j < 16; ++j) s_amp[SW(bc | (j << 8))] = a[j]; } while (0)
#define LOAD_D() do { _Pragma("unroll") for (int jh = 0; jh < 4; ++jh) \
        _Pragma("unroll") for (int c = 0; c < 2; ++c) { \
        int p = SW((jh << 12) | (t << 2) | (2*c)); \
        float4 v = *(const float4*)&s_amp[p]; \
        a[jh*4+2*c] = make_float2(v.x, v.y); a[jh*4+2*c+1] = make_float2(v.z, v.w); } } while (0)
#define STORE_D() do { _Pragma("unroll") for (int jh = 0; jh < 4; ++jh) \
        _Pragma("unroll") for (int c = 0; c < 2; ++c) { \
        int p = SW((jh << 12) | (t << 2) | (2*c)); \
        *(float4*)&s_amp[p] = make_float4(a[jh*4+2*c].x, a[jh*4+2*c].y, a[jh*4+2*c+1].x, a[jh*4+2*c+1].y); } } while (0)

    // ---- P1 (D: bits 12,13,0,1): analytic set0 state; set1 bits 13 then 12 (desc) ----
    {
        float2 F = make_float2(1.f, 0.f);
        #pragma unroll
        for (int bp = 2; bp < 12; ++bp) {
            int b = (t >> (bp - 2)) & 1;
            float4 uu = s_U4[0][13 - bp];
            float2 f = b ? make_float2(-uu.z, uu.w) : make_float2(uu.x, uu.y); // col-0
            F = cmul(F, f);
        }
        float4 u13 = s_U4[0][13], u12 = s_U4[0][12];
        float4 u1q = s_U4[0][1],  u0q = s_U4[0][0];
        float2 c13[2] = { make_float2(u13.x, u13.y), make_float2(-u13.z, u13.w) };
        float2 c12[2] = { make_float2(u12.x, u12.y), make_float2(-u12.z, u12.w) };
        float2 c1q[2] = { make_float2(u1q.x, u1q.y), make_float2(-u1q.z, u1q.w) };
        float2 c0q[2] = { make_float2(u0q.x, u0q.y), make_float2(-u0q.z, u0q.w) };
        float2 g01[4], g23[4];
        #pragma unroll
        for (int j1 = 0; j1 < 2; ++j1)
            #pragma unroll
            for (int j0 = 0; j0 < 2; ++j0)
                g01[(j1 << 1) | j0] = cmul(c13[j0], c12[j1]);
        #pragma unroll
        for (int j3 = 0; j3 < 2; ++j3)
            #pragma unroll
            for (int j2 = 0; j2 < 2; ++j2)
                g23[(j3 << 1) | j2] = cmul(c1q[j2], c0q[j3]);
        float2 Fg[4];
        #pragma unroll
        for (int jl = 0; jl < 4; ++jl) Fg[jl] = cmul(F, g01[jl]);
        #pragma unroll
        for (int j = 0; j < 16; ++j) a[j] = cmul(Fg[j & 3], g23[j >> 2]);
    }
    GATE_BITVJ(3, s_V1, 13, 2);            // g=13, nbr bit12 = reg bit 2
    GATE_BITVU(2, s_V1, 12, (t >> 9) & 1); // g=12, nbr bit11 = t bit 9
    STORE_D(); __syncthreads();

    // ---- P2 (C): set1 bits 11,10,9,8 (desc) ----
    LOAD_C();
    GATE_BITVJ(3, s_V1, 11, 2);
    GATE_BITVJ(2, s_V1, 10, 1);
    GATE_BITVJ(1, s_V1,  9, 0);
    GATE_BITVU(0, s_V1,  8, (t >> 7) & 1); // nbr bit7 = t bit 7
    STORE_C(); __syncthreads();

    // ---- P3 (B): set1 bits 7,6,5,4 (desc) ----
    LOAD_B();
    GATE_BITVJ(3, s_V1, 7, 2);
    GATE_BITVJ(2, s_V1, 6, 1);
    GATE_BITVJ(1, s_V1, 5, 0);
    GATE_BITVU(0, s_V1, 4, (t >> 3) & 1);  // nbr bit3 = t bit 3
    STORE_B(); __syncthreads();

    // ---- P4 (A): set1 bits 3..0 (desc), set2 bits 0..3 (asc), measure 0-2 ----
    LOAD_A();
    GATE_BITVJ(3, s_V1, 3, 2);
    GATE_BITVJ(2, s_V1, 2, 1);
    GATE_BITVJ(1, s_V1, 1, 0);
    GATE_BITVU(0, s_V1, 0, 0);             // g=0 plain
    GATE_BITVJ(0, s_V2, 0, 1);             // nbr bit1 = reg bit 1
    GATE_BITVJ(1, s_V2, 1, 2);
    GATE_BITVJ(2, s_V2, 2, 3);
    GATE_BITVU(3, s_V2, 3, t & 1);         // nbr bit4 = t bit 0
    MEAS(0, 0, ((j >> 1) & 1), 0);
    MEAS(1, 1, ((j >> 2) & 1), (j & 1));
    MEAS(2, 2, ((j >> 3) & 1), ((j >> 1) & 1));
    STORE_A(); __syncthreads();

    // ---- P5 (B): set2 bits 4..7, measure 4-6 ----
    LOAD_B();
    GATE_BITVJ(0, s_V2, 4, 1);
    GATE_BITVJ(1, s_V2, 5, 2);
    GATE_BITVJ(2, s_V2, 6, 3);
    GATE_BITVU(3, s_V2, 7, (t >> 4) & 1);  // nbr bit8 = t bit 4
    MEAS(4, 0, ((j >> 1) & 1), ((t >> 3) & 1));
    MEAS(5, 1, ((j >> 2) & 1), (j & 1));
    MEAS(6, 2, ((j >> 3) & 1), ((j >> 1) & 1));
    STORE_B(); __syncthreads();

    // ---- P6 (C): set2 bits 8..11, measure 8-10 ----
    LOAD_C();
    GATE_BITVJ(0, s_V2,  8, 1);
    GATE_BITVJ(1, s_V2,  9, 2);
    GATE_BITVJ(2, s_V2, 10, 3);
    GATE_BITVU(3, s_V2, 11, (t >> 8) & 1); // nbr bit12 = t bit 8
    MEAS(8, 0, ((j >> 1) & 1), ((t >> 7) & 1));
    MEAS(9, 1, ((j >> 2) & 1), (j & 1));
    MEAS(10, 2, ((j >> 3) & 1), ((j >> 1) & 1));
    STORE_C(); __syncthreads();

    // ---- P7 (D): set2 bits 12,13, measure 12,13 ----
    LOAD_D();
    GATE_BITVJ(2, s_V2, 12, 3);            // nbr bit13 = reg bit 3
    GATE_BITVU(3, s_V2, 13, 0);            // g=13 plain
    MEAS(12, 2, ((j >> 3) & 1), ((t >> 9) & 1));
    MEAS(13, 3, 0, ((j >> 2) & 1));
    STORE_D(); __syncthreads();

    // ---- P8 (E: bits 2,3,7,11): measure 3,7,11 (load only) ----
    {
        int kb = (t & 3) | (((t >> 2) & 7) << 4) | (((t >> 5) & 7) << 8) | (((t >> 8) & 3) << 12);
        int exor = ((t >> 2) & 7) << 1;
        #pragma unroll
        for (int j = 0; j < 16; ++j) {
            int k = kb | ((j & 3) << 2) | (((j >> 2) & 1) << 7) | (((j >> 3) & 1) << 11);
            a[j] = s_amp[k ^ exor];
        }
        MEAS(3,  1, ((t >> 2) & 1), (j & 1));
        MEAS(7,  2, ((t >> 5) & 1), ((t >> 4) & 1));
        MEAS(11, 3, ((t >> 8) & 1), ((t >> 7) & 1));
    }

    // ---- block reduction ----
    #pragma unroll
    for (int off = 32; off > 0; off >>= 1)
        acc += __shfl_down(acc, off);
    if ((t & 63) == 0) s_red[t >> 6] = acc;
    __syncthreads();
    if (t == 0) {
        float s = 0.0f;
        #pragma unroll
        for (int w = 0; w < 16; ++w) s += s_red[w];
        out[n] = s;
    }
}

extern "C" void kernel_launch(void* const* d_in, const int* in_sizes, int n_in,
                              void* d_out, int out_size, void* d_ws, size_t ws_size,
                              hipStream_t stream) {
    const float* x    = (const float*)d_in[0];
    const float* psq  = (const float*)d_in[1];
    const float* p2q  = (const float*)d_in[2];
    const float* penc = (const float*)d_in[3];
    const float* pcl  = (const float*)d_in[4];
    float* out = (float*)d_out;
    pqc_kernel<<<NB, NT, 0, stream>>>(x, psq, p2q, penc, pcl, out);
}

// Round 13
// 14.351 us; speedup vs baseline: 3.4255x; 2.4355x over previous
//
#include <hip/hip_runtime.h>
#include <math.h>

#define NQ_     14
#define NB      256
#define NPAIR   13
#define NT      896   // 14 waves = 14 cones

__device__ __forceinline__ float2 cmul(float2 a, float2 b) {
    return make_float2(a.x*b.x - a.y*b.y, a.x*b.y + a.y*b.x);
}

// SU(2) local gate on the (a0,a1) register pair (bit 6 of the window).
__device__ __forceinline__ void g2s(float2& a0, float2& a1, float2 u00, float2 u01) {
    float2 b0, b1;
    b0.x =  u00.x*a0.x - u00.y*a0.y + u01.x*a1.x - u01.y*a1.y;
    b0.y =  u00.x*a0.y + u00.y*a0.x + u01.x*a1.y + u01.y*a1.x;
    b1.x = -u01.x*a0.x - u01.y*a0.y + u00.x*a1.x + u00.y*a1.y;
    b1.y = -u01.x*a0.y + u01.y*a0.x + u00.x*a1.y - u00.y*a1.x;
    a0 = b0; a1 = b1;
}

__global__ __launch_bounds__(NT, 1) void pqc_kernel(
    const float* __restrict__ x,     // (256, 28)
    const float* __restrict__ psq,   // (3, 2, 14, 3)
    const float* __restrict__ p2q,   // (3, 196)
    const float* __restrict__ penc,  // (3, 196)
    const float* __restrict__ pcl,   // (14,)
    float* __restrict__ out)         // (256,)
{
    __shared__ float4 s_U4[4][NQ_];      // merged gate sets (u00,u01), SU(2), indexed by QUBIT
    __shared__ float2 s_T[8][3][64];     // diag pair-bit cis tables per window start w0, layer l
    __shared__ float  s_theta[3][NPAIR];
    __shared__ float  s_red[14];

    const int n = blockIdx.x;
    const int t = threadIdx.x;

    // ---------- phase 1: theta + merged gate matrices (identical to r12 build) ----------
    if (t < 3 * NPAIR) {
        int l = t / NPAIR, p = t - l * NPAIR;
        const float* xr = x + n * 28;
        float feat = xr[2*p] * xr[2*p+2] + xr[2*p+1] * xr[2*p+3];
        int pf = 15 * p + 1;
        s_theta[l][p] = p2q[l*196 + pf] + penc[l*196 + pf] * feat;
    } else if (t >= 64 && t < 64 + 4 * NQ_) {
        // set0 = U0(L0); set1 = U0(L1)*U1(L0); set2 = U0(L2)*U1(L1); set3 = U1(L2)
        int j = t - 64;
        int set = j / NQ_;
        int q = j - set * NQ_;
        auto build = [&](int l, int s, float2 Uo[4]) {
            const float* a = psq + ((l * 2 + s) * NQ_ + q) * 3;
            float phi = a[0], th = a[1], om = a[2];
            float sh, ch; sincosf(0.5f * th, &sh, &ch);
            float sa, ca; sincosf(0.5f * (phi + om), &sa, &ca);
            float sb, cb; sincosf(0.5f * (phi - om), &sb, &cb);
            Uo[0] = make_float2( ch * ca, -ch * sa);
            Uo[1] = make_float2(-sh * cb, -sh * sb);
            Uo[2] = make_float2( sh * cb, -sh * sb);
            Uo[3] = make_float2( ch * ca,  ch * sa);
        };
        float2 M0, M1;
        if (set == 0) {
            float2 T[4]; build(0, 0, T); M0 = T[0]; M1 = T[1];
        } else if (set == 3) {
            float2 T[4]; build(2, 1, T); M0 = T[0]; M1 = T[1];
        } else {
            float2 A[4], Bm[4];
            build(set, 0, A);        // second
            build(set - 1, 1, Bm);   // first
            M0.x = A[0].x*Bm[0].x - A[0].y*Bm[0].y + A[1].x*Bm[2].x - A[1].y*Bm[2].y;
            M0.y = A[0].x*Bm[0].y + A[0].y*Bm[0].x + A[1].x*Bm[2].y + A[1].y*Bm[2].x;
            M1.x = A[0].x*Bm[1].x - A[0].y*Bm[1].y + A[1].x*Bm[3].x - A[1].y*Bm[3].y;
            M1.y = A[0].x*Bm[1].y + A[0].y*Bm[1].x + A[1].x*Bm[3].y + A[1].y*Bm[3].x;
        }
        s_U4[set][q] = make_float4(M0.x, M0.y, M1.x, M1.y);
    }
    __syncthreads();

    // ---------- phase 2: diag pair-bit cis tables ----------
    // T[w0][l][m] = cis(-0.5 * sum_{i=0..5} theta[l][w0+i] * (1 - 2*m_i)), m_i = b_i ^ b_{i+1}
    for (int e = t; e < 8 * 3 * 64; e += NT) {
        int m = e & 63, rest = e >> 6;
        int l = rest % 3, w0 = rest / 3;
        float s = 0.f;
        #pragma unroll
        for (int i = 0; i < 6; ++i)
            s += s_theta[l][w0 + i] * (1.f - 2.f * ((m >> i) & 1));
        float sn, cs; sincosf(-0.5f * s, &sn, &cs);
        s_T[w0][l][m] = make_float2(cs, sn);
    }
    __syncthreads();

    // ---------- cone simulation: wave w simulates qubit q = w ----------
    const int w = t >> 6;        // wave id = qubit
    const int l = t & 63;        // lane = window bits 0..5; bit 6 is the register pair
    float acc;
    {
        const int q = w;
        int w0 = q - 3; w0 = w0 < 0 ? 0 : (w0 > 7 ? 7 : w0);
        const int p = q - w0;    // q's position in window, 0..6

        float2 a0 = make_float2(l == 0 ? 1.f : 0.f, 0.f);  // |0^7>
        float2 a1 = make_float2(0.f, 0.f);

        // cross-lane gate at compile-time window bit I, set S (qubit w0+I)
#define XGATE(S, I) do { \
        float4 uu = s_U4[S][w0 + (I)]; \
        int hi = (l >> (I)) & 1; \
        float Ax = uu.x, Ay = hi ? -uu.y : uu.y; \
        float Bx = hi ? -uu.z : uu.z, By = uu.w; \
        float2 p0, p1; \
        p0.x = __shfl_xor(a0.x, 1 << (I)); p0.y = __shfl_xor(a0.y, 1 << (I)); \
        p1.x = __shfl_xor(a1.x, 1 << (I)); p1.y = __shfl_xor(a1.y, 1 << (I)); \
        float2 n0, n1; \
        n0.x = Ax*a0.x - Ay*a0.y + Bx*p0.x - By*p0.y; \
        n0.y = Ax*a0.y + Ay*a0.x + Bx*p0.y + By*p0.x; \
        n1.x = Ax*a1.x - Ay*a1.y + Bx*p1.x - By*p1.y; \
        n1.y = Ax*a1.y + Ay*a1.x + Bx*p1.y + By*p1.x; \
        a0 = n0; a1 = n1; \
} while (0)

#define LGATE(S) do { float4 uu = s_U4[S][w0 + 6]; \
        g2s(a0, a1, make_float2(uu.x, uu.y), make_float2(uu.z, uu.w)); } while (0)

#define CDIAG(L) do { int m0 = (l ^ (l >> 1)) & 63; \
        a0 = cmul(a0, s_T[w0][L][m0]); \
        a1 = cmul(a1, s_T[w0][L][m0 ^ 32]); } while (0)

#define CSET(S) do { \
        XGATE(S,0); XGATE(S,1); XGATE(S,2); XGATE(S,3); XGATE(S,4); XGATE(S,5); LGATE(S); \
} while (0)

        CSET(0); CDIAG(0);
        CSET(1); CDIAG(1);
        CSET(2); CDIAG(2);

        // set3 = U1(L2) on q only (others cancel); runtime bit p, wave-uniform branch
        if (p < 6) {
            float4 uu = s_U4[3][q];
            int hi = (l >> p) & 1;
            float Ax = uu.x, Ay = hi ? -uu.y : uu.y;
            float Bx = hi ? -uu.z : uu.z, By = uu.w;
            float2 p0, p1;
            p0.x = __shfl_xor(a0.x, 1 << p); p0.y = __shfl_xor(a0.y, 1 << p);
            p1.x = __shfl_xor(a1.x, 1 << p); p1.y = __shfl_xor(a1.y, 1 << p);
            float2 n0, n1;
            n0.x = Ax*a0.x - Ay*a0.y + Bx*p0.x - By*p0.y;
            n0.y = Ax*a0.y + Ay*a0.x + Bx*p0.y + By*p0.x;
            n1.x = Ax*a1.x - Ay*a1.y + Bx*p1.x - By*p1.y;
            n1.y = Ax*a1.y + Ay*a1.x + Bx*p1.y + By*p1.x;
            a0 = n0; a1 = n1;
        } else {
            float4 uu = s_U4[3][q];
            g2s(a0, a1, make_float2(uu.x, uu.y), make_float2(uu.z, uu.w));
        }

        // measure expZ_q (sign by bit p) and expX_q (pairs across bit p)
        float pr0 = a0.x*a0.x + a0.y*a0.y, pr1 = a1.x*a1.x + a1.y*a1.y;
        float zs, xs;
        if (p == 6) {
            zs = pr0 - pr1;
            xs = 2.f * (a0.x*a1.x + a0.y*a1.y);
        } else {
            float sgn = ((l >> p) & 1) ? -1.f : 1.f;
            zs = sgn * (pr0 + pr1);
            float2 p0, p1;
            p0.x = __shfl_xor(a0.x, 1 << p); p0.y = __shfl_xor(a0.y, 1 << p);
            p1.x = __shfl_xor(a1.x, 1 << p); p1.y = __shfl_xor(a1.y, 1 << p);
            xs = a0.x*p0.x + a0.y*p0.y + a1.x*p1.x + a1.y*p1.y;   // sums to 2*sum_pairs Re
        }
        acc = pcl[q] * zs + pcl[13 - q] * xs;
    }

    // ---- wave reduce, then block reduce over 14 waves ----
    #pragma unroll
    for (int off = 32; off > 0; off >>= 1)
        acc += __shfl_down(acc, off);
    if ((t & 63) == 0) s_red[w] = acc;
    __syncthreads();
    if (t == 0) {
        float s = 0.f;
        #pragma unroll
        for (int i = 0; i < 14; ++i) s += s_red[i];
        out[n] = s;
    }
}

extern "C" void kernel_launch(void* const* d_in, const int* in_sizes, int n_in,
                              void* d_out, int out_size, void* d_ws, size_t ws_size,
                              hipStream_t stream) {
    const float* x    = (const float*)d_in[0];
    const float* psq  = (const float*)d_in[1];
    const float* p2q  = (const float*)d_in[2];
    const float* penc = (const float*)d_in[3];
    const float* pcl  = (const float*)d_in[4];
    float* out = (float*)d_out;
    pqc_kernel<<<NB, NT, 0, stream>>>(x, psq, p2q, penc, pcl, out);
}

// Round 14
// 12.955 us; speedup vs baseline: 3.7946x; 1.1078x over previous
//
#include <hip/hip_runtime.h>
#include <math.h>

#define NQ_     14
#define NB      256
#define NPAIR   13
#define NT      512   // 8 waves = 8 shared windows

__device__ __forceinline__ float2 cmul(float2 a, float2 b) {
    return make_float2(a.x*b.x - a.y*b.y, a.x*b.y + a.y*b.x);
}

// SU(2) local gate on the (a0,a1) register pair (bit 6 of the window).
__device__ __forceinline__ void g2s(float2& a0, float2& a1, float2 u00, float2 u01) {
    float2 b0, b1;
    b0.x =  u00.x*a0.x - u00.y*a0.y + u01.x*a1.x - u01.y*a1.y;
    b0.y =  u00.x*a0.y + u00.y*a0.x + u01.x*a1.y + u01.y*a1.x;
    b1.x = -u01.x*a0.x - u01.y*a0.y + u00.x*a1.x + u00.y*a1.y;
    b1.y = -u01.x*a0.y + u01.y*a0.x + u00.x*a1.y - u00.y*a1.x;
    a0 = b0; a1 = b1;
}

__global__ __launch_bounds__(NT, 1) void pqc_kernel(
    const float* __restrict__ x,     // (256, 28)
    const float* __restrict__ psq,   // (3, 2, 14, 3)
    const float* __restrict__ p2q,   // (3, 196)
    const float* __restrict__ penc,  // (3, 196)
    const float* __restrict__ pcl,   // (14,)
    float* __restrict__ out)         // (256,)
{
    __shared__ float4 s_U4[4][NQ_];      // merged gate sets (u00,u01), SU(2), indexed by QUBIT
    __shared__ float2 s_T[8][3][64];     // diag pair-bit cis tables per window start w0, layer l
    __shared__ float  s_theta[3][NPAIR];
    __shared__ float  s_red[8];

    const int n = blockIdx.x;
    const int t = threadIdx.x;

    // ---------- phase 1: theta + merged gate matrices (identical to r13 build) ----------
    if (t < 3 * NPAIR) {
        int l = t / NPAIR, p = t - l * NPAIR;
        const float* xr = x + n * 28;
        float feat = xr[2*p] * xr[2*p+2] + xr[2*p+1] * xr[2*p+3];
        int pf = 15 * p + 1;
        s_theta[l][p] = p2q[l*196 + pf] + penc[l*196 + pf] * feat;
    } else if (t >= 64 && t < 64 + 4 * NQ_) {
        // set0 = U0(L0); set1 = U0(L1)*U1(L0); set2 = U0(L2)*U1(L1); set3 = U1(L2)
        int j = t - 64;
        int set = j / NQ_;
        int q = j - set * NQ_;
        auto build = [&](int l, int s, float2 Uo[4]) {
            const float* a = psq + ((l * 2 + s) * NQ_ + q) * 3;
            float phi = a[0], th = a[1], om = a[2];
            float sh, ch; sincosf(0.5f * th, &sh, &ch);
            float sa, ca; sincosf(0.5f * (phi + om), &sa, &ca);
            float sb, cb; sincosf(0.5f * (phi - om), &sb, &cb);
            Uo[0] = make_float2( ch * ca, -ch * sa);
            Uo[1] = make_float2(-sh * cb, -sh * sb);
            Uo[2] = make_float2( sh * cb, -sh * sb);
            Uo[3] = make_float2( ch * ca,  ch * sa);
        };
        float2 M0, M1;
        if (set == 0) {
            float2 T[4]; build(0, 0, T); M0 = T[0]; M1 = T[1];
        } else if (set == 3) {
            float2 T[4]; build(2, 1, T); M0 = T[0]; M1 = T[1];
        } else {
            float2 A[4], Bm[4];
            build(set, 0, A);        // second
            build(set - 1, 1, Bm);   // first
            M0.x = A[0].x*Bm[0].x - A[0].y*Bm[0].y + A[1].x*Bm[2].x - A[1].y*Bm[2].y;
            M0.y = A[0].x*Bm[0].y + A[0].y*Bm[0].x + A[1].x*Bm[2].y + A[1].y*Bm[2].x;
            M1.x = A[0].x*Bm[1].x - A[0].y*Bm[1].y + A[1].x*Bm[3].x - A[1].y*Bm[3].y;
            M1.y = A[0].x*Bm[1].y + A[0].y*Bm[1].x + A[1].x*Bm[3].y + A[1].y*Bm[3].x;
        }
        s_U4[set][q] = make_float4(M0.x, M0.y, M1.x, M1.y);
    }
    __syncthreads();

    // ---------- phase 2: diag pair-bit cis tables ----------
    // T[w0][l][m] = cis(-0.5 * sum_{i=0..5} theta[l][w0+i] * (1 - 2*m_i)), m_i = b_i ^ b_{i+1}
    for (int e = t; e < 8 * 3 * 64; e += NT) {
        int m = e & 63, rest = e >> 6;
        int l = rest % 3, w0 = rest / 3;
        float s = 0.f;
        #pragma unroll
        for (int i = 0; i < 6; ++i)
            s += s_theta[l][w0 + i] * (1.f - 2.f * ((m >> i) & 1));
        float sn, cs; sincosf(-0.5f * s, &sn, &cs);
        s_T[w0][l][m] = make_float2(cs, sn);
    }
    __syncthreads();

    // ---------- shared window simulation: wave w simulates window [w, w+6] ----------
    const int w = t >> 6;        // wave id = window start w0
    const int l = t & 63;        // lane = window bits 0..5; bit 6 is the register pair
    const int w0 = w;

    float2 a0 = make_float2(l == 0 ? 1.f : 0.f, 0.f);  // |0^7>
    float2 a1 = make_float2(0.f, 0.f);

    // cross-lane gate at compile-time window bit I, set S (qubit w0+I)
#define XGATE(S, I) do { \
    float4 uu = s_U4[S][w0 + (I)]; \
    int hi = (l >> (I)) & 1; \
    float Ax = uu.x, Ay = hi ? -uu.y : uu.y; \
    float Bx = hi ? -uu.z : uu.z, By = uu.w; \
    float2 p0, p1; \
    p0.x = __shfl_xor(a0.x, 1 << (I)); p0.y = __shfl_xor(a0.y, 1 << (I)); \
    p1.x = __shfl_xor(a1.x, 1 << (I)); p1.y = __shfl_xor(a1.y, 1 << (I)); \
    float2 n0, n1; \
    n0.x = Ax*a0.x - Ay*a0.y + Bx*p0.x - By*p0.y; \
    n0.y = Ax*a0.y + Ay*a0.x + Bx*p0.y + By*p0.x; \
    n1.x = Ax*a1.x - Ay*a1.y + Bx*p1.x - By*p1.y; \
    n1.y = Ax*a1.y + Ay*a1.x + Bx*p1.y + By*p1.x; \
    a0 = n0; a1 = n1; \
} while (0)

#define LGATE(S) do { float4 uu = s_U4[S][w0 + 6]; \
    g2s(a0, a1, make_float2(uu.x, uu.y), make_float2(uu.z, uu.w)); } while (0)

#define CDIAG(L) do { int m0 = (l ^ (l >> 1)) & 63; \
    a0 = cmul(a0, s_T[w0][L][m0]); \
    a1 = cmul(a1, s_T[w0][L][m0 ^ 32]); } while (0)

#define CSET(S) do { \
    XGATE(S,0); XGATE(S,1); XGATE(S,2); XGATE(S,3); XGATE(S,4); XGATE(S,5); LGATE(S); \
} while (0)

    CSET(0); CDIAG(0);
    CSET(1); CDIAG(1);
    CSET(2); CDIAG(2);

    // ---------- per-q epilogue: set3 at position p, measure Z_q and X_q ----------
    float acc = 0.f;
    int qb, qe;
    if (w == 0)      { qb = 0;  qe = 4;  }
    else if (w == 7) { qb = 10; qe = 14; }
    else             { qb = w + 3; qe = w + 4; }

    for (int q = qb; q < qe; ++q) {
        const int p = q - w0;    // 0..6, wave-uniform
        float2 b0 = a0, b1 = a1;
        float4 uu = s_U4[3][q];
        if (p < 6) {
            int hi = (l >> p) & 1;
            float Ax = uu.x, Ay = hi ? -uu.y : uu.y;
            float Bx = hi ? -uu.z : uu.z, By = uu.w;
            float2 p0, p1;
            p0.x = __shfl_xor(b0.x, 1 << p); p0.y = __shfl_xor(b0.y, 1 << p);
            p1.x = __shfl_xor(b1.x, 1 << p); p1.y = __shfl_xor(b1.y, 1 << p);
            float2 n0, n1;
            n0.x = Ax*b0.x - Ay*b0.y + Bx*p0.x - By*p0.y;
            n0.y = Ax*b0.y + Ay*b0.x + Bx*p0.y + By*p0.x;
            n1.x = Ax*b1.x - Ay*b1.y + Bx*p1.x - By*p1.y;
            n1.y = Ax*b1.y + Ay*b1.x + Bx*p1.y + By*p1.x;
            b0 = n0; b1 = n1;
        } else {
            g2s(b0, b1, make_float2(uu.x, uu.y), make_float2(uu.z, uu.w));
        }

        float pr0 = b0.x*b0.x + b0.y*b0.y, pr1 = b1.x*b1.x + b1.y*b1.y;
        float zs, xs;
        if (p == 6) {
            zs = pr0 - pr1;
            xs = 2.f * (b0.x*b1.x + b0.y*b1.y);
        } else {
            float sgn = ((l >> p) & 1) ? -1.f : 1.f;
            zs = sgn * (pr0 + pr1);
            float2 p0, p1;
            p0.x = __shfl_xor(b0.x, 1 << p); p0.y = __shfl_xor(b0.y, 1 << p);
            p1.x = __shfl_xor(b1.x, 1 << p); p1.y = __shfl_xor(b1.y, 1 << p);
            xs = b0.x*p0.x + b0.y*p0.y + b1.x*p1.x + b1.y*p1.y;   // wave-sums to 2*sum_pairs Re
        }
        acc += pcl[q] * zs + pcl[13 - q] * xs;
    }

    // ---- wave reduce, then block reduce over 8 waves ----
    #pragma unroll
    for (int off = 32; off > 0; off >>= 1)
        acc += __shfl_down(acc, off);
    if ((t & 63) == 0) s_red[w] = acc;
    __syncthreads();
    if (t == 0) {
        float s = 0.f;
        #pragma unroll
        for (int i = 0; i < 8; ++i) s += s_red[i];
        out[n] = s;
    }
}

extern "C" void kernel_launch(void* const* d_in, const int* in_sizes, int n_in,
                              void* d_out, int out_size, void* d_ws, size_t ws_size,
                              hipStream_t stream) {
    const float* x    = (const float*)d_in[0];
    const float* psq  = (const float*)d_in[1];
    const float* p2q  = (const float*)d_in[2];
    const float* penc = (const float*)d_in[3];
    const float* pcl  = (const float*)d_in[4];
    float* out = (float*)d_out;
    pqc_kernel<<<NB, NT, 0, stream>>>(x, psq, p2q, penc, pcl, out);
}

// Round 15
// 11.555 us; speedup vs baseline: 4.2544x; 1.1212x over previous
//
#include <hip/hip_runtime.h>
#include <math.h>

#define NQ_     14
#define NB      256
#define NPAIR   13
#define NT      512   // 8 waves = 8 shared windows

__device__ __forceinline__ float2 cmul(float2 a, float2 b) {
    return make_float2(a.x*b.x - a.y*b.y, a.x*b.y + a.y*b.x);
}

// SU(2) local gate on the (a0,a1) register pair (bit 6 of the window).
__device__ __forceinline__ void g2s(float2& a0, float2& a1, float2 u00, float2 u01) {
    float2 b0, b1;
    b0.x =  u00.x*a0.x - u00.y*a0.y + u01.x*a1.x - u01.y*a1.y;
    b0.y =  u00.x*a0.y + u00.y*a0.x + u01.x*a1.y + u01.y*a1.x;
    b1.x = -u01.x*a0.x - u01.y*a0.y + u00.x*a1.x + u00.y*a1.y;
    b1.y = -u01.x*a0.y + u01.y*a0.x + u00.x*a1.y - u00.y*a1.x;
    a0 = b0; a1 = b1;
}

__global__ __launch_bounds__(NT, 1) void pqc_kernel(
    const float* __restrict__ x,     // (256, 28)
    const float* __restrict__ psq,   // (3, 2, 14, 3)
    const float* __restrict__ p2q,   // (3, 196)
    const float* __restrict__ penc,  // (3, 196)
    const float* __restrict__ pcl,   // (14,)
    float* __restrict__ out)         // (256,)
{
    __shared__ float4 s_U4[4][NQ_];      // merged gate sets (u00,u01), SU(2), indexed by QUBIT
    __shared__ float2 s_T[8][3][64];     // diag pair-bit cis tables per window start w0, layer l
    __shared__ float  s_theta[3][NPAIR];
    __shared__ float  s_red[8];

    const int n = blockIdx.x;
    const int t = threadIdx.x;

    // ---------- phase 1: theta + merged gate matrices (fast HW trig) ----------
    if (t < 3 * NPAIR) {
        int l = t / NPAIR, p = t - l * NPAIR;
        const float* xr = x + n * 28;
        float feat = xr[2*p] * xr[2*p+2] + xr[2*p+1] * xr[2*p+3];
        int pf = 15 * p + 1;
        s_theta[l][p] = p2q[l*196 + pf] + penc[l*196 + pf] * feat;
    } else if (t >= 64 && t < 64 + 4 * NQ_) {
        // set0 = U0(L0); set1 = U0(L1)*U1(L0); set2 = U0(L2)*U1(L1); set3 = U1(L2)
        int j = t - 64;
        int set = j / NQ_;
        int q = j - set * NQ_;
        auto build = [&](int l, int s, float2 Uo[4]) {
            const float* a = psq + ((l * 2 + s) * NQ_ + q) * 3;
            float phi = a[0], th = a[1], om = a[2];
            float sh, ch; __sincosf(0.5f * th, &sh, &ch);
            float sa, ca; __sincosf(0.5f * (phi + om), &sa, &ca);
            float sb, cb; __sincosf(0.5f * (phi - om), &sb, &cb);
            Uo[0] = make_float2( ch * ca, -ch * sa);
            Uo[1] = make_float2(-sh * cb, -sh * sb);
            Uo[2] = make_float2( sh * cb, -sh * sb);
            Uo[3] = make_float2( ch * ca,  ch * sa);
        };
        float2 M0, M1;
        if (set == 0) {
            float2 T[4]; build(0, 0, T); M0 = T[0]; M1 = T[1];
        } else if (set == 3) {
            float2 T[4]; build(2, 1, T); M0 = T[0]; M1 = T[1];
        } else {
            float2 A[4], Bm[4];
            build(set, 0, A);        // second
            build(set - 1, 1, Bm);   // first
            M0.x = A[0].x*Bm[0].x - A[0].y*Bm[0].y + A[1].x*Bm[2].x - A[1].y*Bm[2].y;
            M0.y = A[0].x*Bm[0].y + A[0].y*Bm[0].x + A[1].x*Bm[2].y + A[1].y*Bm[2].x;
            M1.x = A[0].x*Bm[1].x - A[0].y*Bm[1].y + A[1].x*Bm[3].x - A[1].y*Bm[3].y;
            M1.y = A[0].x*Bm[1].y + A[0].y*Bm[1].x + A[1].x*Bm[3].y + A[1].y*Bm[3].x;
        }
        s_U4[set][q] = make_float4(M0.x, M0.y, M1.x, M1.y);
    }
    __syncthreads();

    // ---------- phase 2: diag pair-bit cis tables ----------
    // T[w0][l][m] = cis(-0.5 * sum_{i=0..5} theta[l][w0+i] * (1 - 2*m_i)), m_i = b_i ^ b_{i+1}
    for (int e = t; e < 8 * 3 * 64; e += NT) {
        int m = e & 63, rest = e >> 6;
        int l = rest % 3, w0 = rest / 3;
        float s = 0.f;
        #pragma unroll
        for (int i = 0; i < 6; ++i)
            s += s_theta[l][w0 + i] * (1.f - 2.f * ((m >> i) & 1));
        float sn, cs; __sincosf(-0.5f * s, &sn, &cs);
        s_T[w0][l][m] = make_float2(cs, sn);
    }
    __syncthreads();

    // ---------- shared window simulation: wave w simulates window [w, w+6] ----------
    const int w = t >> 6;        // wave id = window start w0
    const int l = t & 63;        // lane = window bits 0..5; bit 6 is the register pair
    const int w0 = w;

    float2 a0 = make_float2(l == 0 ? 1.f : 0.f, 0.f);  // |0^7>
    float2 a1 = make_float2(0.f, 0.f);

    // cross-lane gate at compile-time window bit I, set S (qubit w0+I)
#define XGATE(S, I) do { \
    float4 uu = s_U4[S][w0 + (I)]; \
    int hi = (l >> (I)) & 1; \
    float Ax = uu.x, Ay = hi ? -uu.y : uu.y; \
    float Bx = hi ? -uu.z : uu.z, By = uu.w; \
    float2 p0, p1; \
    p0.x = __shfl_xor(a0.x, 1 << (I)); p0.y = __shfl_xor(a0.y, 1 << (I)); \
    p1.x = __shfl_xor(a1.x, 1 << (I)); p1.y = __shfl_xor(a1.y, 1 << (I)); \
    float2 n0, n1; \
    n0.x = Ax*a0.x - Ay*a0.y + Bx*p0.x - By*p0.y; \
    n0.y = Ax*a0.y + Ay*a0.x + Bx*p0.y + By*p0.x; \
    n1.x = Ax*a1.x - Ay*a1.y + Bx*p1.x - By*p1.y; \
    n1.y = Ax*a1.y + Ay*a1.x + Bx*p1.y + By*p1.x; \
    a0 = n0; a1 = n1; \
} while (0)

#define LGATE(S) do { float4 uu = s_U4[S][w0 + 6]; \
    g2s(a0, a1, make_float2(uu.x, uu.y), make_float2(uu.z, uu.w)); } while (0)

#define CDIAG(L) do { int m0 = (l ^ (l >> 1)) & 63; \
    a0 = cmul(a0, s_T[w0][L][m0]); \
    a1 = cmul(a1, s_T[w0][L][m0 ^ 32]); } while (0)

#define CSET(S) do { \
    XGATE(S,0); XGATE(S,1); XGATE(S,2); XGATE(S,3); XGATE(S,4); XGATE(S,5); LGATE(S); \
} while (0)

    CSET(0); CDIAG(0);
    CSET(1); CDIAG(1);
    CSET(2); CDIAG(2);

    // ---------- per-q epilogue: set3 at position p, measure Z_q and X_q ----------
    float acc = 0.f;
    int qb, qe;
    if (w == 0)      { qb = 0;  qe = 4;  }
    else if (w == 7) { qb = 10; qe = 14; }
    else             { qb = w + 3; qe = w + 4; }

    for (int q = qb; q < qe; ++q) {
        const int p = q - w0;    // 0..6, wave-uniform
        float2 b0 = a0, b1 = a1;
        float4 uu = s_U4[3][q];
        if (p < 6) {
            int hi = (l >> p) & 1;
            float Ax = uu.x, Ay = hi ? -uu.y : uu.y;
            float Bx = hi ? -uu.z : uu.z, By = uu.w;
            float2 p0, p1;
            p0.x = __shfl_xor(b0.x, 1 << p); p0.y = __shfl_xor(b0.y, 1 << p);
            p1.x = __shfl_xor(b1.x, 1 << p); p1.y = __shfl_xor(b1.y, 1 << p);
            float2 n0, n1;
            n0.x = Ax*b0.x - Ay*b0.y + Bx*p0.x - By*p0.y;
            n0.y = Ax*b0.y + Ay*b0.x + Bx*p0.y + By*p0.x;
            n1.x = Ax*b1.x - Ay*b1.y + Bx*p1.x - By*p1.y;
            n1.y = Ax*b1.y + Ay*b1.x + Bx*p1.y + By*p1.x;
            b0 = n0; b1 = n1;
        } else {
            g2s(b0, b1, make_float2(uu.x, uu.y), make_float2(uu.z, uu.w));
        }

        float pr0 = b0.x*b0.x + b0.y*b0.y, pr1 = b1.x*b1.x + b1.y*b1.y;
        float zs, xs;
        if (p == 6) {
            zs = pr0 - pr1;
            xs = 2.f * (b0.x*b1.x + b0.y*b1.y);
        } else {
            float sgn = ((l >> p) & 1) ? -1.f : 1.f;
            zs = sgn * (pr0 + pr1);
            float2 p0, p1;
            p0.x = __shfl_xor(b0.x, 1 << p); p0.y = __shfl_xor(b0.y, 1 << p);
            p1.x = __shfl_xor(b1.x, 1 << p); p1.y = __shfl_xor(b1.y, 1 << p);
            xs = b0.x*p0.x + b0.y*p0.y + b1.x*p1.x + b1.y*p1.y;   // wave-sums to 2*sum_pairs Re
        }
        acc += pcl[q] * zs + pcl[13 - q] * xs;
    }

    // ---- wave reduce, then block reduce over 8 waves ----
    #pragma unroll
    for (int off = 32; off > 0; off >>= 1)
        acc += __shfl_down(acc, off);
    if ((t & 63) == 0) s_red[w] = acc;
    __syncthreads();
    if (t == 0) {
        float s = 0.f;
        #pragma unroll
        for (int i = 0; i < 8; ++i) s += s_red[i];
        out[n] = s;
    }
}

extern "C" void kernel_launch(void* const* d_in, const int* in_sizes, int n_in,
                              void* d_out, int out_size, void* d_ws, size_t ws_size,
                              hipStream_t stream) {
    const float* x    = (const float*)d_in[0];
    const float* psq  = (const float*)d_in[1];
    const float* p2q  = (const float*)d_in[2];
    const float* penc = (const float*)d_in[3];
    const float* pcl  = (const float*)d_in[4];
    float* out = (float*)d_out;
    pqc_kernel<<<NB, NT, 0, stream>>>(x, psq, p2q, penc, pcl, out);
}

// Round 16
// 11.327 us; speedup vs baseline: 4.3398x; 1.0201x over previous
//
#include <hip/hip_runtime.h>
#include <math.h>

#define NQ_   14
#define NB    256
#define NT    512   // 8 waves = 8 shared windows

__device__ __forceinline__ float2 cmul(float2 a, float2 b) {
    return make_float2(a.x*b.x - a.y*b.y, a.x*b.y + a.y*b.x);
}

// SU(2) local gate on the (a0,a1) register pair (window bit 6).
__device__ __forceinline__ void g2s(float2& a0, float2& a1, float2 u00, float2 u01) {
    float2 b0, b1;
    b0.x =  u00.x*a0.x - u00.y*a0.y + u01.x*a1.x - u01.y*a1.y;
    b0.y =  u00.x*a0.y + u00.y*a0.x + u01.x*a1.y + u01.y*a1.x;
    b1.x = -u01.x*a0.x - u01.y*a0.y + u00.x*a1.x + u00.y*a1.y;
    b1.y = -u01.x*a0.y + u01.y*a0.x + u00.x*a1.y - u00.y*a1.x;
    a0 = b0; a1 = b1;
}

__global__ __launch_bounds__(NT, 1) void pqc_kernel(
    const float* __restrict__ x,     // (256, 28)
    const float* __restrict__ psq,   // (3, 2, 14, 3)
    const float* __restrict__ p2q,   // (3, 196)
    const float* __restrict__ penc,  // (3, 196)
    const float* __restrict__ pcl,   // (14,)
    float* __restrict__ out)         // (256,)
{
    __shared__ float4 s_Uw[8][3][7];   // per-wave window gates, sets 0-2 (u00,u01) SU(2)
    __shared__ float2 s_T[8][3][64];   // per-wave diag pair-bit cis tables
    __shared__ float  s_th[8][3][6];   // per-wave thetas (6 pairs x 3 layers)
    __shared__ float4 s_GW[8][4];      // per-wave epilogue (gamma, Wx, Wy, -) per q-slot
    __shared__ float  s_red[8];

    const int n = blockIdx.x;
    const int t = threadIdx.x;
    const int w = t >> 6;    // wave id = window start w0
    const int l = t & 63;    // lane

    // ---------- phase A: per-wave setup, disjoint LDS slices, no barriers ----------
    if (l < 18) {
        // thetas: L = layer, i = window pair index, global pair p = w+i (<=12)
        int L = l / 6, i = l - 6 * L;
        int p = w + i;
        const float* xr = x + n * 28;
        float feat = xr[2*p]*xr[2*p+2] + xr[2*p+1]*xr[2*p+3];
        int pf = 15*p + 1;
        s_th[w][L][i] = p2q[L*196 + pf] + penc[L*196 + pf] * feat;
    } else if (l < 39) {
        // 21 window gates: set = 0..2, qi = window-local qubit, global q = w+qi
        int g = l - 18;
        int set = g / 7, qi = g - 7*set;
        int q = w + qi;
        auto build = [&](int lyr, int s, float2 Uo[2]) {
            const float* a = psq + ((lyr*2 + s)*NQ_ + q)*3;
            float phi = a[0], th = a[1], om = a[2];
            float sh, ch; __sincosf(0.5f*th, &sh, &ch);
            float sa, ca; __sincosf(0.5f*(phi+om), &sa, &ca);
            float sb, cb; __sincosf(0.5f*(phi-om), &sb, &cb);
            Uo[0] = make_float2( ch*ca, -ch*sa);
            Uo[1] = make_float2(-sh*cb, -sh*sb);
        };
        float2 M0, M1;
        if (set == 0) {
            float2 T[2]; build(0, 0, T); M0 = T[0]; M1 = T[1];
        } else {
            // merged: U0(L_set) * U1(L_set-1), SU(2) closure
            float2 A[2], Bm[2];
            build(set, 0, A);
            build(set - 1, 1, Bm);
            float2 b00 = Bm[0], b01 = Bm[1];
            float2 b10 = make_float2(-b01.x, b01.y), b11 = make_float2(b00.x, -b00.y);
            M0.x = A[0].x*b00.x - A[0].y*b00.y + A[1].x*b10.x - A[1].y*b10.y;
            M0.y = A[0].x*b00.y + A[0].y*b00.x + A[1].x*b10.y + A[1].y*b10.x;
            M1.x = A[0].x*b01.x - A[0].y*b01.y + A[1].x*b11.x - A[1].y*b11.y;
            M1.y = A[0].x*b01.y + A[0].y*b01.x + A[1].x*b11.y + A[1].y*b11.x;
        }
        s_Uw[w][set][qi] = make_float4(M0.x, M0.y, M1.x, M1.y);
    } else if (l < 43) {
        // epilogue observables: set3 (=U1(L2)) rotated into (gamma, W) per q
        int e = l - 39;
        int nqe = (w == 0 || w == 7) ? 4 : 1;
        if (e < nqe) {
            int q = (w == 0) ? e : ((w == 7) ? 10 + e : w + 3);
            const float* a = psq + ((2*2 + 1)*NQ_ + q)*3;
            float phi = a[0], th = a[1], om = a[2];
            float sh, ch; __sincosf(0.5f*th, &sh, &ch);
            float sa, ca; __sincosf(0.5f*(phi+om), &sa, &ca);
            float sb, cb; __sincosf(0.5f*(phi-om), &sb, &cb);
            float2 v00 = make_float2( ch*ca, -ch*sa);
            float2 v01 = make_float2(-sh*cb, -sh*sb);
            float2 v10 = make_float2( sh*cb, -sh*sb);
            float2 v11 = make_float2( ch*ca,  ch*sa);
            float cz = pcl[q], cx = pcl[13 - q];
            float t1x = (v00.x*v01.x + v00.y*v01.y) - (v10.x*v11.x + v10.y*v11.y);
            float t1y = (v00.x*v01.y - v00.y*v01.x) - (v10.x*v11.y - v10.y*v11.x);
            float t2x = (v00.x*v11.x + v00.y*v11.y) + (v10.x*v01.x + v10.y*v01.y);
            float t2y = (v00.x*v11.y - v00.y*v11.x) + (v10.x*v01.y - v10.y*v01.x);
            float gam = cz * ((v00.x*v00.x + v00.y*v00.y) - (v10.x*v10.x + v10.y*v10.y))
                      + 2.f*cx * (v00.x*v10.x + v00.y*v10.y);
            s_GW[w][e] = make_float4(gam, cz*t1x + cx*t2x, cz*t1y + cx*t2y, 0.f);
        }
    }
    // wave-internal LDS ordering (same-wave DS completes in-order; consumers are ds_reads)
    __asm__ volatile("s_waitcnt lgkmcnt(0)" ::: "memory");

    // ---------- phase B: diag pair-bit cis tables (reads s_th) ----------
    #pragma unroll
    for (int L = 0; L < 3; ++L) {
        float s = 0.f;
        #pragma unroll
        for (int i = 0; i < 6; ++i)
            s += s_th[w][L][i] * (1.f - 2.f*((l >> i) & 1));
        float sn, cs; __sincosf(-0.5f*s, &sn, &cs);
        s_T[w][L][l] = make_float2(cs, sn);
    }
    __asm__ volatile("s_waitcnt lgkmcnt(0)" ::: "memory");

    // ---------- window simulation: wave w simulates window [w, w+6] ----------
    float2 a0 = make_float2(l == 0 ? 1.f : 0.f, 0.f);  // |0^7>
    float2 a1 = make_float2(0.f, 0.f);

#define XGATE(S, I) do { \
    float4 uu = s_Uw[w][S][I]; \
    int hi = (l >> (I)) & 1; \
    float Ax = uu.x, Ay = hi ? -uu.y : uu.y; \
    float Bx = hi ? -uu.z : uu.z, By = uu.w; \
    float2 p0, p1; \
    p0.x = __shfl_xor(a0.x, 1 << (I)); p0.y = __shfl_xor(a0.y, 1 << (I)); \
    p1.x = __shfl_xor(a1.x, 1 << (I)); p1.y = __shfl_xor(a1.y, 1 << (I)); \
    float2 n0, n1; \
    n0.x = Ax*a0.x - Ay*a0.y + Bx*p0.x - By*p0.y; \
    n0.y = Ax*a0.y + Ay*a0.x + Bx*p0.y + By*p0.x; \
    n1.x = Ax*a1.x - Ay*a1.y + Bx*p1.x - By*p1.y; \
    n1.y = Ax*a1.y + Ay*a1.x + Bx*p1.y + By*p1.x; \
    a0 = n0; a1 = n1; \
} while (0)

#define LGATE(S) do { float4 uu = s_Uw[w][S][6]; \
    g2s(a0, a1, make_float2(uu.x, uu.y), make_float2(uu.z, uu.w)); } while (0)

#define CDIAG(L) do { int m0 = (l ^ (l >> 1)) & 63; \
    a0 = cmul(a0, s_T[w][L][m0]); \
    a1 = cmul(a1, s_T[w][L][m0 ^ 32]); } while (0)

#define CSET(S) do { \
    XGATE(S,0); XGATE(S,1); XGATE(S,2); XGATE(S,3); XGATE(S,4); XGATE(S,5); LGATE(S); \
} while (0)

    CSET(0); CDIAG(0);
    CSET(1); CDIAG(1);
    CSET(2); CDIAG(2);

    // ---------- epilogue: rotated observable per q (no set3 gate application) ----------
    float acc = 0.f;
    const int nqe = (w == 0 || w == 7) ? 4 : 1;
    const float pr0 = a0.x*a0.x + a0.y*a0.y, pr1 = a1.x*a1.x + a1.y*a1.y;
    for (int e = 0; e < nqe; ++e) {
        int q = (w == 0) ? e : ((w == 7) ? 10 + e : w + 3);
        int p = q - w;                 // window position, wave-uniform
        float4 gw = s_GW[w][e];
        if (p < 6) {
            int hi = (l >> p) & 1;
            float sgn = hi ? -1.f : 1.f;
            float2 p0, p1;
            p0.x = __shfl_xor(a0.x, 1 << p); p0.y = __shfl_xor(a0.y, 1 << p);
            p1.x = __shfl_xor(a1.x, 1 << p); p1.y = __shfl_xor(a1.y, 1 << p);
            // z = conj(a_lo)*a_hi for this pair; zy sign-corrected per side.
            float zx = a0.x*p0.x + a0.y*p0.y + a1.x*p1.x + a1.y*p1.y;
            float zy = sgn * ((a0.x*p0.y - a0.y*p0.x) + (a1.x*p1.y - a1.y*p1.x));
            // wave-sum counts each pair twice -> use W (not 2W)
            acc += gw.x * sgn * (pr0 + pr1) + (gw.y*zx - gw.z*zy);
        } else {
            // p == 6: pair is (a0,a1) in-register, counted once -> 2W
            float zx = a0.x*a1.x + a0.y*a1.y;
            float zy = a0.x*a1.y - a0.y*a1.x;
            acc += gw.x * (pr0 - pr1) + 2.f*(gw.y*zx - gw.z*zy);
        }
    }

    // ---- wave reduce, then block reduce over 8 waves ----
    #pragma unroll
    for (int off = 32; off > 0; off >>= 1)
        acc += __shfl_down(acc, off);
    if (l == 0) s_red[w] = acc;
    __syncthreads();
    if (t == 0) {
        float s = 0.f;
        #pragma unroll
        for (int i = 0; i < 8; ++i) s += s_red[i];
        out[n] = s;
    }
}

extern "C" void kernel_launch(void* const* d_in, const int* in_sizes, int n_in,
                              void* d_out, int out_size, void* d_ws, size_t ws_size,
                              hipStream_t stream) {
    const float* x    = (const float*)d_in[0];
    const float* psq  = (const float*)d_in[1];
    const float* p2q  = (const float*)d_in[2];
    const float* penc = (const float*)d_in[3];
    const float* pcl  = (const float*)d_in[4];
    float* out = (float*)d_out;
    pqc_kernel<<<NB, NT, 0, stream>>>(x, psq, p2q, penc, pcl, out);
}